// Round 10
// baseline (237.028 us; speedup 1.0000x reference)
//
#include <hip/hip_runtime.h>

// ---------------------------------------------------------------------------
// EnhancedBitcoinGCN: 3x GCNConv + LN/residual + (trivial) MHA + MLP head
// Round 9 -> 10 (async-DMA round):
//  * Evidence: k_gemm_in pinned at 44-50us across FOUR structures; compiler
//    always re-sinks hoisted loads (VGPR stuck ~56) -> each wave serializes
//    its ~60 loads; per-CU BW 5 GB/s of ~25.
//  * Fix: global_load_lds (width 16) double-buffered A-tile staging with
//    counted s_waitcnt vmcnt(N) + raw s_barrier (m97/T3-T4 pattern). Loads
//    bypass VGPRs entirely; DMA of tile ks+1 overlaps MFMA of tile ks.
//    OOB rows / K=164 tail chunks redirect the DMA *source* to a zero page.
//  * Applied to k_gemm_in and all three conv GEMMs. Gathers/CSR/tail as r9.
// ---------------------------------------------------------------------------

typedef __attribute__((ext_vector_type(8))) _Float16 f16x8;
typedef __attribute__((ext_vector_type(4))) _Float16 f16x4;
typedef __attribute__((ext_vector_type(4))) float f32x4;

#define GLOAD_LDS16(gp, lp)                                        \
  __builtin_amdgcn_global_load_lds(                                \
      (const __attribute__((address_space(1))) void*)(gp),         \
      (__attribute__((address_space(3))) void*)(lp), 16, 0, 0)

static __device__ __forceinline__ void wait_vm0() {
  asm volatile("s_waitcnt vmcnt(0)" ::: "memory");
}
static __device__ __forceinline__ void wait_vm1() {
  asm volatile("s_waitcnt vmcnt(1)" ::: "memory");
}
static __device__ __forceinline__ void wait_vm2() {
  asm volatile("s_waitcnt vmcnt(2)" ::: "memory");
}

// ---------------- CSR build ----------------
__global__ void k_count(const int* __restrict__ dst, int* __restrict__ counts, int e) {
  int i = blockIdx.x * blockDim.x + threadIdx.x;
  if (i < e) atomicAdd(&counts[dst[i]], 1);
}

__global__ __launch_bounds__(256) void k_scan_part(
    const int* __restrict__ counts, int* __restrict__ bsums, int n) {
  int tid = threadIdx.x;
  int i0 = blockIdx.x * 1024 + tid * 4;
  int s = 0;
#pragma unroll
  for (int k = 0; k < 4; k++) { int i = i0 + k; if (i < n) s += counts[i]; }
#pragma unroll
  for (int d = 1; d < 64; d <<= 1) s += __shfl_xor(s, d);
  __shared__ int wsum[4];
  int lane = tid & 63, w = tid >> 6;
  if (lane == 0) wsum[w] = s;
  __syncthreads();
  if (tid == 0) bsums[blockIdx.x] = wsum[0] + wsum[1] + wsum[2] + wsum[3];
}

__global__ __launch_bounds__(128) void k_scan_top(int* __restrict__ bsums, int nb) {
  int tid = threadIdx.x;
  int orig = (tid < nb) ? bsums[tid] : 0;
  int v = orig;
  int lane = tid & 63, w = tid >> 6;
#pragma unroll
  for (int d = 1; d < 64; d <<= 1) { int t = __shfl_up(v, d); if (lane >= d) v += t; }
  __shared__ int ws[2];
  if (lane == 63) ws[w] = v;
  __syncthreads();
  if (w == 1) v += ws[0];
  if (tid < nb) bsums[tid] = v - orig;  // exclusive
}

// offsets + dinv + (counts -> 0, becoming the fill cursor)
__global__ __launch_bounds__(256) void k_scan_down(
    int* __restrict__ counts, const int* __restrict__ bsums,
    int* __restrict__ offsets, float* __restrict__ dinv, int n, int e) {
  int tid = threadIdx.x;
  int i0 = blockIdx.x * 1024 + tid * 4;
  int c[4]; int tsum = 0;
#pragma unroll
  for (int k = 0; k < 4; k++) { int i = i0 + k; c[k] = (i < n) ? counts[i] : 0; tsum += c[k]; }
  int v = tsum;
  int lane = tid & 63, w = tid >> 6;
#pragma unroll
  for (int d = 1; d < 64; d <<= 1) { int t = __shfl_up(v, d); if (lane >= d) v += t; }
  __shared__ int wsum[4];
  if (lane == 63) wsum[w] = v;
  __syncthreads();
  int wadd = 0;
#pragma unroll
  for (int q = 0; q < 4; q++) if (q < w) wadd += wsum[q];
  int run = (v - tsum) + wadd + bsums[blockIdx.x];
#pragma unroll
  for (int k = 0; k < 4; k++) {
    int i = i0 + k;
    if (i < n) {
      offsets[i] = run;
      dinv[i] = rsqrtf((float)(c[k] + 1));
      counts[i] = 0;  // becomes fill cursor
    }
    run += c[k];
  }
  if (blockIdx.x == 0 && tid == 0) offsets[n] = e;
}

// packed edge record: {src, norm as bits} -> one 8B meta load in gather
__global__ void k_fill(const int* __restrict__ src, const int* __restrict__ dst,
                       const int* __restrict__ offsets, int* __restrict__ cursor,
                       const float* __restrict__ dinv, int2* __restrict__ csr, int e) {
  int i = blockIdx.x * blockDim.x + threadIdx.x;
  if (i >= e) return;
  int s = src[i], d = dst[i];
  int pos = atomicAdd(&cursor[d], 1);
  csr[offsets[d] + pos] = make_int2(s, __float_as_int(dinv[s] * dinv[d]));
}

// ---------------- weight prepack (fragment-ordered fp16, hi only) ----------
// B fragment for mfma_f32_16x16x32_f16: lane l holds B[ks*32+(l>>4)*8+i][ct*16+(l&15)]
// layout: elem[(ks*CT+ct)*512 + lane*8 + i]
__device__ __forceinline__ void pack_hi(const float* __restrict__ W,
                                        _Float16* __restrict__ dst,
                                        int K, int N, int u) {
  int lane = u & 63; int rest = u >> 6; int CT = N >> 4;
  int ct = rest % CT, ks = rest / CT;
  int gcol = ct * 16 + (lane & 15);
  int gk0 = ks * 32 + (lane >> 4) * 8;
  size_t o = (size_t)(ks * CT + ct) * 512 + lane * 8;
#pragma unroll
  for (int i = 0; i < 8; i++) {
    float v = (gk0 + i < K) ? W[(size_t)(gk0 + i) * N + gcol] : 0.0f;
    dst[o + i] = (_Float16)v;
  }
}

// blocks [0,25): prepack (6400 units); blocks [25,..): zero counts (+ zp)
__global__ void k_setup(const float* __restrict__ Wi, const float* __restrict__ Wg1,
                        const float* __restrict__ Wg2, const float* __restrict__ Wg3,
                        _Float16* __restrict__ pWi, _Float16* __restrict__ pWg1,
                        _Float16* __restrict__ pWg2, _Float16* __restrict__ pWg3,
                        int* __restrict__ counts, float* __restrict__ zp, int n) {
  int b = blockIdx.x;
  if (b < 25) {
    int t = b * 256 + threadIdx.x;
    if (t < 3072) pack_hi(Wi, pWi, 164, 128, t);
    else if (t < 5120) pack_hi(Wg1, pWg1, 128, 128, t - 3072);
    else if (t < 6144) pack_hi(Wg2, pWg2, 128, 64, t - 5120);
    else if (t < 6400) pack_hi(Wg3, pWg3, 64, 32, t - 6144);
  } else {
    if (b == 25 && threadIdx.x < 64) zp[threadIdx.x] = 0.0f;
    int i = (b - 25) * 256 + threadIdx.x;
    if (i < n) counts[i] = 0;
  }
}

// ---------------- input GEMM: h = LN(relu(x@Wi+bi)) ----------------
// 512 thr / 8 waves, 128 rows/block. x staged via global_load_lds into a
// double-buffered [128][32] f32 LDS tile (2x16KB). Per wave per step: 2 DMA
// issues of 1KB (uniform LDS base + lane*16). Counted vmcnt overlaps DMA of
// tile ks+1 with MFMA of tile ks. OOB rows / ks=5 tail chunks -> zero page.
__global__ __launch_bounds__(512, 4) void k_gemm_in(
    const float* __restrict__ x, const _Float16* __restrict__ pB,
    const float* __restrict__ bias, const float* __restrict__ gamma,
    const float* __restrict__ beta, const float* __restrict__ zp,
    _Float16* __restrict__ out, int n) {
  constexpr int N = 128, CT = 8;
  __shared__ __align__(16) float sA[2][128 * 32];  // 2 x 16 KB
  int tid = threadIdx.x;
  int lane = tid & 63, w = tid >> 6;
  int base = blockIdx.x * 128;
  const f16x8* Bf = (const f16x8*)pB;

  auto stage = [&](int ks, int buf) {
#pragma unroll
    for (int j = 0; j < 2; j++) {
      int q = (j * 8 + w) * 64 + lane;  // 16B chunk index in tile
      int row = q >> 3;                 // 8 chunks per 128B row
      int c = q & 7;
      int rg = base + row;
      const void* src = (rg < n && (ks < 5 || c == 0))
                            ? (const void*)(x + (size_t)rg * 164 + ks * 32 + c * 4)
                            : (const void*)zp;
      GLOAD_LDS16(src, &sA[buf][(size_t)(j * 8 + w) * 256]);
    }
  };

  f32x4 acc[CT];
#pragma unroll
  for (int c = 0; c < CT; c++) acc[c] = (f32x4)0.0f;

  stage(0, 0);
#pragma unroll
  for (int ks = 0; ks < 6; ks++) {
    if (ks + 1 < 6) { stage(ks + 1, (ks + 1) & 1); wait_vm2(); }
    else wait_vm0();
    __builtin_amdgcn_s_barrier();
    const float4* fr = (const float4*)&sA[ks & 1][((w * 16 + (lane & 15)) * 32) +
                                                 (lane >> 4) * 8];
    float4 u0 = fr[0], u1 = fr[1];
    float v[8] = {u0.x, u0.y, u0.z, u0.w, u1.x, u1.y, u1.z, u1.w};
    f16x8 ah, al;
#pragma unroll
    for (int i = 0; i < 8; i++) {
      ah[i] = (_Float16)v[i];
      al[i] = (_Float16)(v[i] - (float)ah[i]);
    }
#pragma unroll
    for (int c = 0; c < CT; c++) {
      f16x8 b = Bf[(ks * CT + c) * 64 + lane];
      acc[c] = __builtin_amdgcn_mfma_f32_16x16x32_f16(ah, b, acc[c], 0, 0, 0);
      acc[c] = __builtin_amdgcn_mfma_f32_16x16x32_f16(al, b, acc[c], 0, 0, 0);
    }
    __builtin_amdgcn_s_barrier();
  }

  // bias + relu + LN over N cols (row lives in a 16-lane group)
  int r0 = (lane >> 4) * 4;
  int li = lane & 15;
  float s1[4] = {0, 0, 0, 0}, s2[4] = {0, 0, 0, 0};
#pragma unroll
  for (int c = 0; c < CT; c++) {
    float bb = bias[c * 16 + li];
#pragma unroll
    for (int r = 0; r < 4; r++) {
      float t = acc[c][r] + bb;
      t = t > 0.0f ? t : 0.0f;
      acc[c][r] = t;
      s1[r] += t;
      s2[r] += t * t;
    }
  }
#pragma unroll
  for (int m = 1; m < 16; m <<= 1) {
#pragma unroll
    for (int r = 0; r < 4; r++) {
      s1[r] += __shfl_xor(s1[r], m);
      s2[r] += __shfl_xor(s2[r], m);
    }
  }
#pragma unroll
  for (int c = 0; c < CT; c++) {
    float gv = gamma[c * 16 + li], bv = beta[c * 16 + li];
#pragma unroll
    for (int r = 0; r < 4; r++) {
      int node = base + w * 16 + r0 + r;
      if (node < n) {
        float mean = s1[r] * (1.0f / N);
        float var = s2[r] * (1.0f / N) - mean * mean;
        float rs = rsqrtf(var + 1e-5f);
        out[(size_t)node * N + c * 16 + li] =
            (_Float16)((acc[c][r] - mean) * rs * gv + bv);
      }
    }
  }
}

// ---------------- conv GEMM: xw = A@W (fp16 x fp16-hi) ---------------------
// A staged via global_load_lds into double-buffered [128][32] fp16 (2x8KB);
// one 1KB DMA issue per wave per step. B direct from prepacked L2.
template <int K, int N>
__global__ __launch_bounds__(512, 4) void k_gemm_f16(
    const _Float16* __restrict__ A, const _Float16* __restrict__ pB,
    const float* __restrict__ zp, _Float16* __restrict__ out, int n) {
  constexpr int KS = K / 32, CT = N / 16;
  __shared__ __align__(16) _Float16 sA[2][128 * 32];  // 2 x 8 KB
  int tid = threadIdx.x;
  int lane = tid & 63, w = tid >> 6;
  int base = blockIdx.x * 128;
  const f16x8* Bf = (const f16x8*)pB;

  auto stage = [&](int ks, int buf) {
    int q = w * 64 + lane;   // 16B chunk index
    int row = q >> 2;        // 4 chunks per 64B row
    int c = q & 3;
    int rg = base + row;
    const void* src = (rg < n) ? (const void*)(A + (size_t)rg * K + ks * 32 + c * 8)
                               : (const void*)zp;
    GLOAD_LDS16(src, &sA[buf][(size_t)w * 512]);
  };

  f32x4 acc[CT];
#pragma unroll
  for (int c = 0; c < CT; c++) acc[c] = (f32x4)0.0f;

  stage(0, 0);
#pragma unroll
  for (int ks = 0; ks < KS; ks++) {
    if (ks + 1 < KS) { stage(ks + 1, (ks + 1) & 1); wait_vm1(); }
    else wait_vm0();
    __builtin_amdgcn_s_barrier();
    f16x8 av = *(const f16x8*)&sA[ks & 1][((w * 16 + (lane & 15)) * 32) +
                                          (lane >> 4) * 8];
#pragma unroll
    for (int c = 0; c < CT; c++) {
      f16x8 b = Bf[(ks * CT + c) * 64 + lane];
      acc[c] = __builtin_amdgcn_mfma_f32_16x16x32_f16(av, b, acc[c], 0, 0, 0);
    }
    __builtin_amdgcn_s_barrier();
  }

  int r0 = (lane >> 4) * 4;
  int li = lane & 15;
#pragma unroll
  for (int c = 0; c < CT; c++) {
#pragma unroll
    for (int r = 0; r < 4; r++) {
      int node = base + w * 16 + r0 + r;
      if (node < n) out[(size_t)node * N + c * 16 + li] = (_Float16)acc[c][r];
    }
  }
}

// ---------------- dst-side gather, 4 cols/thread, 8-deep load batches ------
// MODE 0: out = relu(agg) + auxh[node]      (conv1)
// MODE 1: out = LN(relu(agg); gamma, beta)  (conv2)
// MODE 2: out = agg                         (conv3; tail applies relu)
template <int OUT_D, int MODE>
__global__ __launch_bounds__(256, 2) void k_gather(
    const int* __restrict__ off, const int2* __restrict__ csr,
    const _Float16* __restrict__ xw, const float* __restrict__ dinv,
    const float* __restrict__ bias, const _Float16* __restrict__ auxh,
    const float* __restrict__ gamma, const float* __restrict__ beta,
    _Float16* __restrict__ out, int n) {
  constexpr int TPN = OUT_D / 4;   // threads per node (32/16/8)
  constexpr int NPB = 256 / TPN;
  int tid = threadIdx.x;
  int node = blockIdx.x * NPB + tid / TPN;
  int li = tid % TPN;
  if (node >= n) return;
  int start = off[node], end = off[node + 1];
  float di = dinv[node];
  float d2 = di * di;
  const _Float16* xp = xw + 4 * li;
  f16x4 self = *(const f16x4*)(xp + (size_t)node * OUT_D);
  f16x4 hres;
  if constexpr (MODE == 0)
    hres = *(const f16x4*)(auxh + (size_t)node * OUT_D + 4 * li);
  float a0 = (float)self[0] * d2 + bias[4 * li + 0];
  float a1 = (float)self[1] * d2 + bias[4 * li + 1];
  float a2 = (float)self[2] * d2 + bias[4 * li + 2];
  float a3 = (float)self[3] * d2 + bias[4 * li + 3];
  for (int cb = start; cb < end; cb += TPN) {
    int m = end - cb; if (m > TPN) m = TPN;
    int sv = node; float nv = 0.0f;                 // pad: self row, weight 0
    if (li < m) { int2 me = csr[cb + li]; sv = me.x; nv = __int_as_float(me.y); }
    for (int j0 = 0; j0 < m; j0 += 8) {
      int s0 = __shfl(sv, j0 + 0, TPN), s1 = __shfl(sv, j0 + 1, TPN);
      int s2 = __shfl(sv, j0 + 2, TPN), s3 = __shfl(sv, j0 + 3, TPN);
      int s4 = __shfl(sv, j0 + 4, TPN), s5 = __shfl(sv, j0 + 5, TPN);
      int s6 = __shfl(sv, j0 + 6, TPN), s7 = __shfl(sv, j0 + 7, TPN);
      float w0 = __shfl(nv, j0 + 0, TPN), w1 = __shfl(nv, j0 + 1, TPN);
      float w2 = __shfl(nv, j0 + 2, TPN), w3 = __shfl(nv, j0 + 3, TPN);
      float w4 = __shfl(nv, j0 + 4, TPN), w5 = __shfl(nv, j0 + 5, TPN);
      float w6 = __shfl(nv, j0 + 6, TPN), w7 = __shfl(nv, j0 + 7, TPN);
      f16x4 v0 = *(const f16x4*)(xp + (size_t)s0 * OUT_D);
      f16x4 v1 = *(const f16x4*)(xp + (size_t)s1 * OUT_D);
      f16x4 v2 = *(const f16x4*)(xp + (size_t)s2 * OUT_D);
      f16x4 v3 = *(const f16x4*)(xp + (size_t)s3 * OUT_D);
      f16x4 v4 = *(const f16x4*)(xp + (size_t)s4 * OUT_D);
      f16x4 v5 = *(const f16x4*)(xp + (size_t)s5 * OUT_D);
      f16x4 v6 = *(const f16x4*)(xp + (size_t)s6 * OUT_D);
      f16x4 v7 = *(const f16x4*)(xp + (size_t)s7 * OUT_D);
      a0 += (float)v0[0] * w0 + (float)v1[0] * w1 + (float)v2[0] * w2 + (float)v3[0] * w3
          + (float)v4[0] * w4 + (float)v5[0] * w5 + (float)v6[0] * w6 + (float)v7[0] * w7;
      a1 += (float)v0[1] * w0 + (float)v1[1] * w1 + (float)v2[1] * w2 + (float)v3[1] * w3
          + (float)v4[1] * w4 + (float)v5[1] * w5 + (float)v6[1] * w6 + (float)v7[1] * w7;
      a2 += (float)v0[2] * w0 + (float)v1[2] * w1 + (float)v2[2] * w2 + (float)v3[2] * w3
          + (float)v4[2] * w4 + (float)v5[2] * w5 + (float)v6[2] * w6 + (float)v7[2] * w7;
      a3 += (float)v0[3] * w0 + (float)v1[3] * w1 + (float)v2[3] * w2 + (float)v3[3] * w3
          + (float)v4[3] * w4 + (float)v5[3] * w5 + (float)v6[3] * w6 + (float)v7[3] * w7;
    }
  }
  _Float16* po = out + (size_t)node * OUT_D + 4 * li;
  if constexpr (MODE == 0) {
    f16x4 o;
    o[0] = (_Float16)((a0 > 0.0f ? a0 : 0.0f) + (float)hres[0]);
    o[1] = (_Float16)((a1 > 0.0f ? a1 : 0.0f) + (float)hres[1]);
    o[2] = (_Float16)((a2 > 0.0f ? a2 : 0.0f) + (float)hres[2]);
    o[3] = (_Float16)((a3 > 0.0f ? a3 : 0.0f) + (float)hres[3]);
    *(f16x4*)po = o;
  } else if constexpr (MODE == 1) {
    float v0 = a0 > 0.0f ? a0 : 0.0f, v1 = a1 > 0.0f ? a1 : 0.0f;
    float v2 = a2 > 0.0f ? a2 : 0.0f, v3 = a3 > 0.0f ? a3 : 0.0f;
    float s1 = v0 + v1 + v2 + v3;
    float s2 = v0 * v0 + v1 * v1 + v2 * v2 + v3 * v3;
#pragma unroll
    for (int d = 1; d < TPN; d <<= 1) {
      s1 += __shfl_xor(s1, d, TPN);
      s2 += __shfl_xor(s2, d, TPN);
    }
    float m_ = s1 * (1.0f / OUT_D);
    float var = s2 * (1.0f / OUT_D) - m_ * m_;
    float rs = rsqrtf(var + 1e-5f);
    f16x4 o;
    o[0] = (_Float16)((v0 - m_) * rs * gamma[4 * li + 0] + beta[4 * li + 0]);
    o[1] = (_Float16)((v1 - m_) * rs * gamma[4 * li + 1] + beta[4 * li + 1]);
    o[2] = (_Float16)((v2 - m_) * rs * gamma[4 * li + 2] + beta[4 * li + 2]);
    o[3] = (_Float16)((v3 - m_) * rs * gamma[4 * li + 3] + beta[4 * li + 3]);
    *(f16x4*)po = o;
  } else {
    f16x4 o;
    o[0] = (_Float16)a0; o[1] = (_Float16)a1;
    o[2] = (_Float16)a2; o[3] = (_Float16)a3;
    *(f16x4*)po = o;
  }
}

// ---------------- tail: relu(agg3) -> Wv -> Wo -> Wc1 -> Wc2 -> Wc3 --------
// (MHA with seq_len==1: softmax over one key == 1, so out = (x@Wv+bv)@Wo+bo)
__global__ __launch_bounds__(256) void k_tail(
    const _Float16* __restrict__ agg3, const float* __restrict__ Wv,
    const float* __restrict__ bv, const float* __restrict__ Wo,
    const float* __restrict__ bo, const float* __restrict__ Wc1,
    const float* __restrict__ bc1, const float* __restrict__ Wc2,
    const float* __restrict__ bc2, const float* __restrict__ Wc3,
    const float* __restrict__ bc3, float* __restrict__ out, int n) {
  __shared__ float sWv[1024], sWo[1024], sWc1[512], sWc2[512];
  __shared__ float sbv[32], sbo[32], sbc2[32], sWc3[32], sbc1[16], sbc3[1];
  int tid = threadIdx.x;
  for (int i = tid; i < 1024; i += 256) { sWv[i] = Wv[i]; sWo[i] = Wo[i]; }
  for (int i = tid; i < 512; i += 256) { sWc1[i] = Wc1[i]; sWc2[i] = Wc2[i]; }
  if (tid < 32) { sbv[tid] = bv[tid]; sbo[tid] = bo[tid];
                  sbc2[tid] = bc2[tid]; sWc3[tid] = Wc3[tid]; }
  if (tid < 16) sbc1[tid] = bc1[tid];
  if (tid == 0) sbc3[0] = bc3[0];
  __syncthreads();
  int node = blockIdx.x * blockDim.x + tid;
  if (node >= n) return;
  float a[32];
  const f16x8* row8 = (const f16x8*)(agg3 + (size_t)node * 32);
#pragma unroll
  for (int q = 0; q < 4; q++) {
    f16x8 t = row8[q];
#pragma unroll
    for (int i = 0; i < 8; i++) {
      float f = (float)t[i];
      a[8 * q + i] = f > 0.0f ? f : 0.0f;
    }
  }
  float v[32];
#pragma unroll
  for (int j = 0; j < 32; j++) v[j] = sbv[j];
  for (int k = 0; k < 32; k++) {
#pragma unroll
    for (int j = 0; j < 32; j++) v[j] += a[k] * sWv[k * 32 + j];
  }
  float o[32];
#pragma unroll
  for (int j = 0; j < 32; j++) o[j] = sbo[j];
  for (int k = 0; k < 32; k++) {
#pragma unroll
    for (int j = 0; j < 32; j++) o[j] += v[k] * sWo[k * 32 + j];
  }
  float c1[16];
#pragma unroll
  for (int j = 0; j < 16; j++) c1[j] = sbc1[j];
  for (int k = 0; k < 32; k++) {
#pragma unroll
    for (int j = 0; j < 16; j++) c1[j] += o[k] * sWc1[k * 16 + j];
  }
#pragma unroll
  for (int j = 0; j < 16; j++) c1[j] = c1[j] > 0.0f ? c1[j] : 0.0f;
  float c2[32];
#pragma unroll
  for (int j = 0; j < 32; j++) c2[j] = sbc2[j];
  for (int k = 0; k < 16; k++) {
#pragma unroll
    for (int j = 0; j < 32; j++) c2[j] += c1[k] * sWc2[k * 32 + j];
  }
  float r = sbc3[0];
#pragma unroll
  for (int k = 0; k < 32; k++) {
    float c = c2[k] > 0.0f ? c2[k] : 0.0f;
    r += c * sWc3[k];
  }
  out[node] = r;
}

// ---------------------------------------------------------------------------
extern "C" void kernel_launch(void* const* d_in, const int* in_sizes, int n_in,
                              void* d_out, int out_size, void* d_ws, size_t ws_size,
                              hipStream_t stream) {
  const float* x   = (const float*)d_in[0];
  const int* ei    = (const int*)d_in[1];
  const float* Wi  = (const float*)d_in[2];
  const float* bi  = (const float*)d_in[3];
  const float* g1  = (const float*)d_in[4];
  const float* b1  = (const float*)d_in[5];
  const float* Wg1 = (const float*)d_in[6];
  const float* bg1 = (const float*)d_in[7];
  const float* Wg2 = (const float*)d_in[8];
  const float* bg2 = (const float*)d_in[9];
  const float* g2  = (const float*)d_in[10];
  const float* b2  = (const float*)d_in[11];
  const float* Wg3 = (const float*)d_in[12];
  const float* bg3 = (const float*)d_in[13];
  // d_in[14..17]: Wq,bq,Wk,bk — mathematically dead (softmax over 1 key == 1)
  const float* Wv  = (const float*)d_in[18];
  const float* bv  = (const float*)d_in[19];
  const float* Wo  = (const float*)d_in[20];
  const float* bo  = (const float*)d_in[21];
  const float* Wc1 = (const float*)d_in[22];
  const float* bc1 = (const float*)d_in[23];
  const float* Wc2 = (const float*)d_in[24];
  const float* bc2 = (const float*)d_in[25];
  const float* Wc3 = (const float*)d_in[26];
  const float* bc3 = (const float*)d_in[27];

  const int n = in_sizes[0] / 164;
  const int e = in_sizes[1] / 2;
  const int* src = ei;
  const int* dst = ei + e;

  // workspace layout (256B aligned)
  char* ws = (char*)d_ws;
  size_t off = 0;
  auto alloc = [&](size_t bytes) {
    char* p = ws + off;
    off += (bytes + 255) & ~(size_t)255;
    return p;
  };
  _Float16* A     = (_Float16*)alloc((size_t)n * 128 * 2);
  _Float16* B     = (_Float16*)alloc((size_t)n * 128 * 2);
  _Float16* C     = (_Float16*)alloc((size_t)n * 128 * 2);
  float* dinv     = (float*)alloc((size_t)n * 4);
  int*   counts   = (int*)alloc((size_t)n * 4);      // reused as fill cursor
  int*   offsets  = (int*)alloc((size_t)(n + 1) * 4);
  int*   bsums    = (int*)alloc(128 * 4);
  int2*  csr      = (int2*)alloc((size_t)e * 8);
  _Float16* pWi   = (_Float16*)alloc(3072 * 16);   // 48 KB
  _Float16* pWg1  = (_Float16*)alloc(2048 * 16);   // 32 KB
  _Float16* pWg2  = (_Float16*)alloc(1024 * 16);   // 16 KB
  _Float16* pWg3  = (_Float16*)alloc(256 * 16);    // 4 KB
  float* zp       = (float*)alloc(64 * 4);         // zero page for OOB DMA
  (void)ws_size;

  const int BS = 256;
  const int SB = (n + 1023) / 1024;  // scan blocks (98 for n=100k, <=128)
  const int GB = (n + 127) / 128;    // gemm blocks (512 thr, 128 rows)

  // ---- setup: weight prepack + zero counts + zero page ----
  k_setup<<<25 + (n + 255) / 256, 256, 0, stream>>>(
      Wi, Wg1, Wg2, Wg3, pWi, pWg1, pWg2, pWg3, counts, zp, n);

  // ---- CSR build (shared by all three convs) ----
  k_count<<<(e + BS - 1) / BS, BS, 0, stream>>>(dst, counts, e);
  k_scan_part<<<SB, 256, 0, stream>>>(counts, bsums, n);
  k_scan_top<<<1, 128, 0, stream>>>(bsums, SB);
  k_scan_down<<<SB, 256, 0, stream>>>(counts, bsums, offsets, dinv, n, e);
  k_fill<<<(e + BS - 1) / BS, BS, 0, stream>>>(src, dst, offsets, counts, dinv,
                                               csr, e);

  // ---- input layer: A = h = LN(relu(x@Wi+bi))  [fp16] ----
  k_gemm_in<<<GB, 512, 0, stream>>>(x, pWi, bi, g1, b1, zp, A, n);

  // ---- conv1: B = xw1 = h@Wg1; gather -> C = h1 = relu(agg)+h ----
  k_gemm_f16<128, 128><<<GB, 512, 0, stream>>>(A, pWg1, zp, B, n);
  k_gather<128, 0><<<(n + 7) / 8, 256, 0, stream>>>(
      offsets, csr, B, dinv, bg1, A, nullptr, nullptr, C, n);

  // ---- conv2: A = xw2 = h1@Wg2 [n,64]; gather -> B = h2 = LN(relu(agg)) ----
  k_gemm_f16<128, 64><<<GB, 512, 0, stream>>>(C, pWg2, zp, A, n);
  k_gather<64, 1><<<(n + 15) / 16, 256, 0, stream>>>(
      offsets, csr, A, dinv, bg2, nullptr, g2, b2, B, n);

  // ---- conv3: A = xw3 = h2@Wg3 [n,32]; gather -> C = agg3 [fp16] ----
  k_gemm_f16<64, 32><<<GB, 512, 0, stream>>>(B, pWg3, zp, A, n);
  k_gather<32, 2><<<(n + 31) / 32, 256, 0, stream>>>(
      offsets, csr, A, dinv, bg3, nullptr, nullptr, nullptr, C, n);

  // ---- tail: relu(agg3) -> MHA(v,o) -> MLP -> out ----
  k_tail<<<(n + BS - 1) / BS, BS, 0, stream>>>(
      C, Wv, bv, Wo, bo, Wc1, bc1, Wc2, bc2, Wc3, bc3, (float*)d_out, n);
}

// Round 11
// 227.446 us; speedup vs baseline: 1.0421x; 1.0421x over previous
//
#include <hip/hip_runtime.h>

// ---------------------------------------------------------------------------
// EnhancedBitcoinGCN: 3x GCNConv + LN/residual + (trivial) MHA + MLP head
// Round 10 -> 11 (barrier-free wave-private pipeline):
//  * Evidence: grid fits in one residency wave -> kernel dur == per-block
//    dur; 2 barriers/K-step made every step's critical path the SLOWEST
//    wave's DMA (200-900cy variance). Plus 900K LDS bank conflicts from
//    the [row][32] tile (16-way on ds_read_b128).
//  * Fix: each wave owns its 16 rows; per K-step DMAs 1-2KB into a
//    wave-PRIVATE double-buffered LDS slot (global_load_lds: compiler
//    cannot sink it), ordered only by per-wave counted vmcnt. ZERO
//    barriers in the loop. Issue order: B(ks) loads -> DMA(ks+1) ->
//    vmcnt(1|2). XOR chunk swizzle on DMA source + ds_read kills the
//    bank conflicts (linear dest + pre-swizzled source, m173 pattern).
//  * Gathers / CSR build / tail unchanged.
// ---------------------------------------------------------------------------

typedef __attribute__((ext_vector_type(8))) _Float16 f16x8;
typedef __attribute__((ext_vector_type(4))) _Float16 f16x4;
typedef __attribute__((ext_vector_type(4))) float f32x4;

#define GLOAD_LDS16(gp, lp)                                        \
  __builtin_amdgcn_global_load_lds(                                \
      (const __attribute__((address_space(1))) void*)(gp),         \
      (__attribute__((address_space(3))) void*)(lp), 16, 0, 0)

static __device__ __forceinline__ void wait_vm0() {
  asm volatile("s_waitcnt vmcnt(0)" ::: "memory");
}
static __device__ __forceinline__ void wait_vm1() {
  asm volatile("s_waitcnt vmcnt(1)" ::: "memory");
}
static __device__ __forceinline__ void wait_vm2() {
  asm volatile("s_waitcnt vmcnt(2)" ::: "memory");
}

// ---------------- CSR build ----------------
__global__ void k_count(const int* __restrict__ dst, int* __restrict__ counts, int e) {
  int i = blockIdx.x * blockDim.x + threadIdx.x;
  if (i < e) atomicAdd(&counts[dst[i]], 1);
}

__global__ __launch_bounds__(256) void k_scan_part(
    const int* __restrict__ counts, int* __restrict__ bsums, int n) {
  int tid = threadIdx.x;
  int i0 = blockIdx.x * 1024 + tid * 4;
  int s = 0;
#pragma unroll
  for (int k = 0; k < 4; k++) { int i = i0 + k; if (i < n) s += counts[i]; }
#pragma unroll
  for (int d = 1; d < 64; d <<= 1) s += __shfl_xor(s, d);
  __shared__ int wsum[4];
  int lane = tid & 63, w = tid >> 6;
  if (lane == 0) wsum[w] = s;
  __syncthreads();
  if (tid == 0) bsums[blockIdx.x] = wsum[0] + wsum[1] + wsum[2] + wsum[3];
}

__global__ __launch_bounds__(128) void k_scan_top(int* __restrict__ bsums, int nb) {
  int tid = threadIdx.x;
  int orig = (tid < nb) ? bsums[tid] : 0;
  int v = orig;
  int lane = tid & 63, w = tid >> 6;
#pragma unroll
  for (int d = 1; d < 64; d <<= 1) { int t = __shfl_up(v, d); if (lane >= d) v += t; }
  __shared__ int ws[2];
  if (lane == 63) ws[w] = v;
  __syncthreads();
  if (w == 1) v += ws[0];
  if (tid < nb) bsums[tid] = v - orig;  // exclusive
}

// offsets + dinv + (counts -> 0, becoming the fill cursor)
__global__ __launch_bounds__(256) void k_scan_down(
    int* __restrict__ counts, const int* __restrict__ bsums,
    int* __restrict__ offsets, float* __restrict__ dinv, int n, int e) {
  int tid = threadIdx.x;
  int i0 = blockIdx.x * 1024 + tid * 4;
  int c[4]; int tsum = 0;
#pragma unroll
  for (int k = 0; k < 4; k++) { int i = i0 + k; c[k] = (i < n) ? counts[i] : 0; tsum += c[k]; }
  int v = tsum;
  int lane = tid & 63, w = tid >> 6;
#pragma unroll
  for (int d = 1; d < 64; d <<= 1) { int t = __shfl_up(v, d); if (lane >= d) v += t; }
  __shared__ int wsum[4];
  if (lane == 63) wsum[w] = v;
  __syncthreads();
  int wadd = 0;
#pragma unroll
  for (int q = 0; q < 4; q++) if (q < w) wadd += wsum[q];
  int run = (v - tsum) + wadd + bsums[blockIdx.x];
#pragma unroll
  for (int k = 0; k < 4; k++) {
    int i = i0 + k;
    if (i < n) {
      offsets[i] = run;
      dinv[i] = rsqrtf((float)(c[k] + 1));
      counts[i] = 0;  // becomes fill cursor
    }
    run += c[k];
  }
  if (blockIdx.x == 0 && tid == 0) offsets[n] = e;
}

// packed edge record: {src, norm as bits} -> one 8B meta load in gather
__global__ void k_fill(const int* __restrict__ src, const int* __restrict__ dst,
                       const int* __restrict__ offsets, int* __restrict__ cursor,
                       const float* __restrict__ dinv, int2* __restrict__ csr, int e) {
  int i = blockIdx.x * blockDim.x + threadIdx.x;
  if (i >= e) return;
  int s = src[i], d = dst[i];
  int pos = atomicAdd(&cursor[d], 1);
  csr[offsets[d] + pos] = make_int2(s, __float_as_int(dinv[s] * dinv[d]));
}

// ---------------- weight prepack (fragment-ordered fp16, hi only) ----------
// B fragment for mfma_f32_16x16x32_f16: lane l holds B[ks*32+(l>>4)*8+i][ct*16+(l&15)]
// layout: elem[(ks*CT+ct)*512 + lane*8 + i]
__device__ __forceinline__ void pack_hi(const float* __restrict__ W,
                                        _Float16* __restrict__ dst,
                                        int K, int N, int u) {
  int lane = u & 63; int rest = u >> 6; int CT = N >> 4;
  int ct = rest % CT, ks = rest / CT;
  int gcol = ct * 16 + (lane & 15);
  int gk0 = ks * 32 + (lane >> 4) * 8;
  size_t o = (size_t)(ks * CT + ct) * 512 + lane * 8;
#pragma unroll
  for (int i = 0; i < 8; i++) {
    float v = (gk0 + i < K) ? W[(size_t)(gk0 + i) * N + gcol] : 0.0f;
    dst[o + i] = (_Float16)v;
  }
}

// blocks [0,25): prepack (6400 units); blocks [25,..): zero counts (+ zp)
__global__ void k_setup(const float* __restrict__ Wi, const float* __restrict__ Wg1,
                        const float* __restrict__ Wg2, const float* __restrict__ Wg3,
                        _Float16* __restrict__ pWi, _Float16* __restrict__ pWg1,
                        _Float16* __restrict__ pWg2, _Float16* __restrict__ pWg3,
                        int* __restrict__ counts, float* __restrict__ zp, int n) {
  int b = blockIdx.x;
  if (b < 25) {
    int t = b * 256 + threadIdx.x;
    if (t < 3072) pack_hi(Wi, pWi, 164, 128, t);
    else if (t < 5120) pack_hi(Wg1, pWg1, 128, 128, t - 3072);
    else if (t < 6144) pack_hi(Wg2, pWg2, 128, 64, t - 5120);
    else if (t < 6400) pack_hi(Wg3, pWg3, 64, 32, t - 6144);
  } else {
    if (b == 25 && threadIdx.x < 64) zp[threadIdx.x] = 0.0f;
    int i = (b - 25) * 256 + threadIdx.x;
    if (i < n) counts[i] = 0;
  }
}

// ---------------- input GEMM: h = LN(relu(x@Wi+bi)) ----------------
// 512 thr / 8 waves, 128 rows/block, barrier-FREE. Each wave DMAs its own
// 16x32-f32 slice (2KB, 2 issues) into a wave-private double buffer; only
// per-wave counted vmcnt orders the pipeline. XOR chunk swizzle (src side)
// de-conflicts the ds_read (lanes 0-15 spread across banks).
__global__ __launch_bounds__(512, 4) void k_gemm_in(
    const float* __restrict__ x, const _Float16* __restrict__ pB,
    const float* __restrict__ bias, const float* __restrict__ gamma,
    const float* __restrict__ beta, const float* __restrict__ zp,
    _Float16* __restrict__ out, int n) {
  constexpr int N = 128, CT = 8;
  __shared__ __align__(16) float sAi[8][2][512];  // 8 waves x 2 bufs x 2KB
  int tid = threadIdx.x;
  int lane = tid & 63, w = tid >> 6;
  int rowbase = blockIdx.x * 128 + w * 16;
  const f16x8* Bf = (const f16x8*)pB;

  auto stage = [&](int ks, int buf) {
#pragma unroll
    for (int j = 0; j < 2; j++) {
      int r_ = j * 8 + (lane >> 3);           // row in wave slice
      int c_ = (lane & 7) ^ (lane >> 3);      // swizzled source chunk
      int rg = rowbase + r_;
      bool ok = (rg < n) && (ks < 5 || c_ == 0);
      const void* s = ok ? (const void*)(x + (size_t)rg * 164 + ks * 32 + c_ * 4)
                         : (const void*)zp;
      GLOAD_LDS16(s, &sAi[w][buf][j * 256]);
    }
  };

  f32x4 acc[CT];
#pragma unroll
  for (int c = 0; c < CT; c++) acc[c] = (f32x4)0.0f;

  int rr = lane & 15;
  int c0 = (lane >> 4) * 2;
  int s0 = c0 ^ (rr & 7);
  int s1 = (c0 + 1) ^ (rr & 7);

  stage(0, 0);
#pragma unroll
  for (int ks = 0; ks < 6; ks++) {
    f16x8 bfr[CT];
#pragma unroll
    for (int c = 0; c < CT; c++) bfr[c] = Bf[(ks * CT + c) * 64 + lane];
    if (ks + 1 < 6) { stage(ks + 1, (ks + 1) & 1); wait_vm2(); }
    else wait_vm0();
    const float* bp = &sAi[w][ks & 1][0];
    float4 u0 = *(const float4*)&bp[rr * 32 + s0 * 4];
    float4 u1 = *(const float4*)&bp[rr * 32 + s1 * 4];
    float v[8] = {u0.x, u0.y, u0.z, u0.w, u1.x, u1.y, u1.z, u1.w};
    f16x8 ah, al;
#pragma unroll
    for (int i = 0; i < 8; i++) {
      ah[i] = (_Float16)v[i];
      al[i] = (_Float16)(v[i] - (float)ah[i]);
    }
#pragma unroll
    for (int c = 0; c < CT; c++) {
      acc[c] = __builtin_amdgcn_mfma_f32_16x16x32_f16(ah, bfr[c], acc[c], 0, 0, 0);
      acc[c] = __builtin_amdgcn_mfma_f32_16x16x32_f16(al, bfr[c], acc[c], 0, 0, 0);
    }
  }

  // bias + relu + LN over N cols (row lives in a 16-lane group; wave-local)
  int r0 = (lane >> 4) * 4;
  int li = lane & 15;
  float s1v[4] = {0, 0, 0, 0}, s2v[4] = {0, 0, 0, 0};
#pragma unroll
  for (int c = 0; c < CT; c++) {
    float bb = bias[c * 16 + li];
#pragma unroll
    for (int r = 0; r < 4; r++) {
      float t = acc[c][r] + bb;
      t = t > 0.0f ? t : 0.0f;
      acc[c][r] = t;
      s1v[r] += t;
      s2v[r] += t * t;
    }
  }
#pragma unroll
  for (int m = 1; m < 16; m <<= 1) {
#pragma unroll
    for (int r = 0; r < 4; r++) {
      s1v[r] += __shfl_xor(s1v[r], m);
      s2v[r] += __shfl_xor(s2v[r], m);
    }
  }
#pragma unroll
  for (int c = 0; c < CT; c++) {
    float gv = gamma[c * 16 + li], bv = beta[c * 16 + li];
#pragma unroll
    for (int r = 0; r < 4; r++) {
      int node = rowbase + r0 + r;
      if (node < n) {
        float mean = s1v[r] * (1.0f / N);
        float var = s2v[r] * (1.0f / N) - mean * mean;
        float rs = rsqrtf(var + 1e-5f);
        out[(size_t)node * N + c * 16 + li] =
            (_Float16)((acc[c][r] - mean) * rs * gv + bv);
      }
    }
  }
}

// ---------------- conv GEMM: xw = A@W (fp16 x fp16-hi) ---------------------
// Barrier-free wave-private pipeline; 16x32-fp16 slice (1KB, 1 DMA issue)
// per wave per K-step; XOR chunk swizzle on src + ds_read.
template <int K, int N>
__global__ __launch_bounds__(512, 4) void k_gemm_f16(
    const _Float16* __restrict__ A, const _Float16* __restrict__ pB,
    const float* __restrict__ zp, _Float16* __restrict__ out, int n) {
  constexpr int KS = K / 32, CT = N / 16;
  __shared__ __align__(16) _Float16 sA[8][2][512];  // 8 waves x 2 bufs x 1KB
  int tid = threadIdx.x;
  int lane = tid & 63, w = tid >> 6;
  int rowbase = blockIdx.x * 128 + w * 16;
  const f16x8* Bf = (const f16x8*)pB;

  int r_ = lane >> 2;                       // row in wave slice
  int c_ = (lane & 3) ^ (r_ & 3);           // swizzled source chunk
  int rg = rowbase + r_;
  const _Float16* asrc = A + (size_t)rg * K + c_ * 8;
  bool rok = rg < n;

  auto stage = [&](int ks, int buf) {
    const void* s = rok ? (const void*)(asrc + ks * 32) : (const void*)zp;
    GLOAD_LDS16(s, &sA[w][buf][0]);
  };

  f32x4 acc[CT];
#pragma unroll
  for (int c = 0; c < CT; c++) acc[c] = (f32x4)0.0f;

  int rr = lane & 15;
  int slot = (lane >> 4) ^ (rr & 3);

  stage(0, 0);
#pragma unroll
  for (int ks = 0; ks < KS; ks++) {
    f16x8 bfr[CT];
#pragma unroll
    for (int c = 0; c < CT; c++) bfr[c] = Bf[(ks * CT + c) * 64 + lane];
    if (ks + 1 < KS) { stage(ks + 1, (ks + 1) & 1); wait_vm1(); }
    else wait_vm0();
    f16x8 av = *(const f16x8*)&sA[w][ks & 1][rr * 32 + slot * 8];
#pragma unroll
    for (int c = 0; c < CT; c++) {
      acc[c] = __builtin_amdgcn_mfma_f32_16x16x32_f16(av, bfr[c], acc[c], 0, 0, 0);
    }
  }

  int r0 = (lane >> 4) * 4;
  int li = lane & 15;
#pragma unroll
  for (int c = 0; c < CT; c++) {
#pragma unroll
    for (int r = 0; r < 4; r++) {
      int node = rowbase + r0 + r;
      if (node < n) out[(size_t)node * N + c * 16 + li] = (_Float16)acc[c][r];
    }
  }
}

// ---------------- dst-side gather, 4 cols/thread, 8-deep load batches ------
// MODE 0: out = relu(agg) + auxh[node]      (conv1)
// MODE 1: out = LN(relu(agg); gamma, beta)  (conv2)
// MODE 2: out = agg                         (conv3; tail applies relu)
template <int OUT_D, int MODE>
__global__ __launch_bounds__(256, 2) void k_gather(
    const int* __restrict__ off, const int2* __restrict__ csr,
    const _Float16* __restrict__ xw, const float* __restrict__ dinv,
    const float* __restrict__ bias, const _Float16* __restrict__ auxh,
    const float* __restrict__ gamma, const float* __restrict__ beta,
    _Float16* __restrict__ out, int n) {
  constexpr int TPN = OUT_D / 4;   // threads per node (32/16/8)
  constexpr int NPB = 256 / TPN;
  int tid = threadIdx.x;
  int node = blockIdx.x * NPB + tid / TPN;
  int li = tid % TPN;
  if (node >= n) return;
  int start = off[node], end = off[node + 1];
  float di = dinv[node];
  float d2 = di * di;
  const _Float16* xp = xw + 4 * li;
  f16x4 self = *(const f16x4*)(xp + (size_t)node * OUT_D);
  f16x4 hres;
  if constexpr (MODE == 0)
    hres = *(const f16x4*)(auxh + (size_t)node * OUT_D + 4 * li);
  float a0 = (float)self[0] * d2 + bias[4 * li + 0];
  float a1 = (float)self[1] * d2 + bias[4 * li + 1];
  float a2 = (float)self[2] * d2 + bias[4 * li + 2];
  float a3 = (float)self[3] * d2 + bias[4 * li + 3];
  for (int cb = start; cb < end; cb += TPN) {
    int m = end - cb; if (m > TPN) m = TPN;
    int sv = node; float nv = 0.0f;                 // pad: self row, weight 0
    if (li < m) { int2 me = csr[cb + li]; sv = me.x; nv = __int_as_float(me.y); }
    for (int j0 = 0; j0 < m; j0 += 8) {
      int s0 = __shfl(sv, j0 + 0, TPN), s1 = __shfl(sv, j0 + 1, TPN);
      int s2 = __shfl(sv, j0 + 2, TPN), s3 = __shfl(sv, j0 + 3, TPN);
      int s4 = __shfl(sv, j0 + 4, TPN), s5 = __shfl(sv, j0 + 5, TPN);
      int s6 = __shfl(sv, j0 + 6, TPN), s7 = __shfl(sv, j0 + 7, TPN);
      float w0 = __shfl(nv, j0 + 0, TPN), w1 = __shfl(nv, j0 + 1, TPN);
      float w2 = __shfl(nv, j0 + 2, TPN), w3 = __shfl(nv, j0 + 3, TPN);
      float w4 = __shfl(nv, j0 + 4, TPN), w5 = __shfl(nv, j0 + 5, TPN);
      float w6 = __shfl(nv, j0 + 6, TPN), w7 = __shfl(nv, j0 + 7, TPN);
      f16x4 v0 = *(const f16x4*)(xp + (size_t)s0 * OUT_D);
      f16x4 v1 = *(const f16x4*)(xp + (size_t)s1 * OUT_D);
      f16x4 v2 = *(const f16x4*)(xp + (size_t)s2 * OUT_D);
      f16x4 v3 = *(const f16x4*)(xp + (size_t)s3 * OUT_D);
      f16x4 v4 = *(const f16x4*)(xp + (size_t)s4 * OUT_D);
      f16x4 v5 = *(const f16x4*)(xp + (size_t)s5 * OUT_D);
      f16x4 v6 = *(const f16x4*)(xp + (size_t)s6 * OUT_D);
      f16x4 v7 = *(const f16x4*)(xp + (size_t)s7 * OUT_D);
      a0 += (float)v0[0] * w0 + (float)v1[0] * w1 + (float)v2[0] * w2 + (float)v3[0] * w3
          + (float)v4[0] * w4 + (float)v5[0] * w5 + (float)v6[0] * w6 + (float)v7[0] * w7;
      a1 += (float)v0[1] * w0 + (float)v1[1] * w1 + (float)v2[1] * w2 + (float)v3[1] * w3
          + (float)v4[1] * w4 + (float)v5[1] * w5 + (float)v6[1] * w6 + (float)v7[1] * w7;
      a2 += (float)v0[2] * w0 + (float)v1[2] * w1 + (float)v2[2] * w2 + (float)v3[2] * w3
          + (float)v4[2] * w4 + (float)v5[2] * w5 + (float)v6[2] * w6 + (float)v7[2] * w7;
      a3 += (float)v0[3] * w0 + (float)v1[3] * w1 + (float)v2[3] * w2 + (float)v3[3] * w3
          + (float)v4[3] * w4 + (float)v5[3] * w5 + (float)v6[3] * w6 + (float)v7[3] * w7;
    }
  }
  _Float16* po = out + (size_t)node * OUT_D + 4 * li;
  if constexpr (MODE == 0) {
    f16x4 o;
    o[0] = (_Float16)((a0 > 0.0f ? a0 : 0.0f) + (float)hres[0]);
    o[1] = (_Float16)((a1 > 0.0f ? a1 : 0.0f) + (float)hres[1]);
    o[2] = (_Float16)((a2 > 0.0f ? a2 : 0.0f) + (float)hres[2]);
    o[3] = (_Float16)((a3 > 0.0f ? a3 : 0.0f) + (float)hres[3]);
    *(f16x4*)po = o;
  } else if constexpr (MODE == 1) {
    float v0 = a0 > 0.0f ? a0 : 0.0f, v1 = a1 > 0.0f ? a1 : 0.0f;
    float v2 = a2 > 0.0f ? a2 : 0.0f, v3 = a3 > 0.0f ? a3 : 0.0f;
    float s1 = v0 + v1 + v2 + v3;
    float s2 = v0 * v0 + v1 * v1 + v2 * v2 + v3 * v3;
#pragma unroll
    for (int d = 1; d < TPN; d <<= 1) {
      s1 += __shfl_xor(s1, d, TPN);
      s2 += __shfl_xor(s2, d, TPN);
    }
    float m_ = s1 * (1.0f / OUT_D);
    float var = s2 * (1.0f / OUT_D) - m_ * m_;
    float rs = rsqrtf(var + 1e-5f);
    f16x4 o;
    o[0] = (_Float16)((v0 - m_) * rs * gamma[4 * li + 0] + beta[4 * li + 0]);
    o[1] = (_Float16)((v1 - m_) * rs * gamma[4 * li + 1] + beta[4 * li + 1]);
    o[2] = (_Float16)((v2 - m_) * rs * gamma[4 * li + 2] + beta[4 * li + 2]);
    o[3] = (_Float16)((v3 - m_) * rs * gamma[4 * li + 3] + beta[4 * li + 3]);
    *(f16x4*)po = o;
  } else {
    f16x4 o;
    o[0] = (_Float16)a0; o[1] = (_Float16)a1;
    o[2] = (_Float16)a2; o[3] = (_Float16)a3;
    *(f16x4*)po = o;
  }
}

// ---------------- tail: relu(agg3) -> Wv -> Wo -> Wc1 -> Wc2 -> Wc3 --------
// (MHA with seq_len==1: softmax over one key == 1, so out = (x@Wv+bv)@Wo+bo)
__global__ __launch_bounds__(256) void k_tail(
    const _Float16* __restrict__ agg3, const float* __restrict__ Wv,
    const float* __restrict__ bv, const float* __restrict__ Wo,
    const float* __restrict__ bo, const float* __restrict__ Wc1,
    const float* __restrict__ bc1, const float* __restrict__ Wc2,
    const float* __restrict__ bc2, const float* __restrict__ Wc3,
    const float* __restrict__ bc3, float* __restrict__ out, int n) {
  __shared__ float sWv[1024], sWo[1024], sWc1[512], sWc2[512];
  __shared__ float sbv[32], sbo[32], sbc2[32], sWc3[32], sbc1[16], sbc3[1];
  int tid = threadIdx.x;
  for (int i = tid; i < 1024; i += 256) { sWv[i] = Wv[i]; sWo[i] = Wo[i]; }
  for (int i = tid; i < 512; i += 256) { sWc1[i] = Wc1[i]; sWc2[i] = Wc2[i]; }
  if (tid < 32) { sbv[tid] = bv[tid]; sbo[tid] = bo[tid];
                  sbc2[tid] = bc2[tid]; sWc3[tid] = Wc3[tid]; }
  if (tid < 16) sbc1[tid] = bc1[tid];
  if (tid == 0) sbc3[0] = bc3[0];
  __syncthreads();
  int node = blockIdx.x * blockDim.x + tid;
  if (node >= n) return;
  float a[32];
  const f16x8* row8 = (const f16x8*)(agg3 + (size_t)node * 32);
#pragma unroll
  for (int q = 0; q < 4; q++) {
    f16x8 t = row8[q];
#pragma unroll
    for (int i = 0; i < 8; i++) {
      float f = (float)t[i];
      a[8 * q + i] = f > 0.0f ? f : 0.0f;
    }
  }
  float v[32];
#pragma unroll
  for (int j = 0; j < 32; j++) v[j] = sbv[j];
  for (int k = 0; k < 32; k++) {
#pragma unroll
    for (int j = 0; j < 32; j++) v[j] += a[k] * sWv[k * 32 + j];
  }
  float o[32];
#pragma unroll
  for (int j = 0; j < 32; j++) o[j] = sbo[j];
  for (int k = 0; k < 32; k++) {
#pragma unroll
    for (int j = 0; j < 32; j++) o[j] += v[k] * sWo[k * 32 + j];
  }
  float c1[16];
#pragma unroll
  for (int j = 0; j < 16; j++) c1[j] = sbc1[j];
  for (int k = 0; k < 32; k++) {
#pragma unroll
    for (int j = 0; j < 16; j++) c1[j] += o[k] * sWc1[k * 16 + j];
  }
#pragma unroll
  for (int j = 0; j < 16; j++) c1[j] = c1[j] > 0.0f ? c1[j] : 0.0f;
  float c2[32];
#pragma unroll
  for (int j = 0; j < 32; j++) c2[j] = sbc2[j];
  for (int k = 0; k < 16; k++) {
#pragma unroll
    for (int j = 0; j < 32; j++) c2[j] += c1[k] * sWc2[k * 32 + j];
  }
  float r = sbc3[0];
#pragma unroll
  for (int k = 0; k < 32; k++) {
    float c = c2[k] > 0.0f ? c2[k] : 0.0f;
    r += c * sWc3[k];
  }
  out[node] = r;
}

// ---------------------------------------------------------------------------
extern "C" void kernel_launch(void* const* d_in, const int* in_sizes, int n_in,
                              void* d_out, int out_size, void* d_ws, size_t ws_size,
                              hipStream_t stream) {
  const float* x   = (const float*)d_in[0];
  const int* ei    = (const int*)d_in[1];
  const float* Wi  = (const float*)d_in[2];
  const float* bi  = (const float*)d_in[3];
  const float* g1  = (const float*)d_in[4];
  const float* b1  = (const float*)d_in[5];
  const float* Wg1 = (const float*)d_in[6];
  const float* bg1 = (const float*)d_in[7];
  const float* Wg2 = (const float*)d_in[8];
  const float* bg2 = (const float*)d_in[9];
  const float* g2  = (const float*)d_in[10];
  const float* b2  = (const float*)d_in[11];
  const float* Wg3 = (const float*)d_in[12];
  const float* bg3 = (const float*)d_in[13];
  // d_in[14..17]: Wq,bq,Wk,bk — mathematically dead (softmax over 1 key == 1)
  const float* Wv  = (const float*)d_in[18];
  const float* bv  = (const float*)d_in[19];
  const float* Wo  = (const float*)d_in[20];
  const float* bo  = (const float*)d_in[21];
  const float* Wc1 = (const float*)d_in[22];
  const float* bc1 = (const float*)d_in[23];
  const float* Wc2 = (const float*)d_in[24];
  const float* bc2 = (const float*)d_in[25];
  const float* Wc3 = (const float*)d_in[26];
  const float* bc3 = (const float*)d_in[27];

  const int n = in_sizes[0] / 164;
  const int e = in_sizes[1] / 2;
  const int* src = ei;
  const int* dst = ei + e;

  // workspace layout (256B aligned)
  char* ws = (char*)d_ws;
  size_t off = 0;
  auto alloc = [&](size_t bytes) {
    char* p = ws + off;
    off += (bytes + 255) & ~(size_t)255;
    return p;
  };
  _Float16* A     = (_Float16*)alloc((size_t)n * 128 * 2);
  _Float16* B     = (_Float16*)alloc((size_t)n * 128 * 2);
  _Float16* C     = (_Float16*)alloc((size_t)n * 128 * 2);
  float* dinv     = (float*)alloc((size_t)n * 4);
  int*   counts   = (int*)alloc((size_t)n * 4);      // reused as fill cursor
  int*   offsets  = (int*)alloc((size_t)(n + 1) * 4);
  int*   bsums    = (int*)alloc(128 * 4);
  int2*  csr      = (int2*)alloc((size_t)e * 8);
  _Float16* pWi   = (_Float16*)alloc(3072 * 16);   // 48 KB
  _Float16* pWg1  = (_Float16*)alloc(2048 * 16);   // 32 KB
  _Float16* pWg2  = (_Float16*)alloc(1024 * 16);   // 16 KB
  _Float16* pWg3  = (_Float16*)alloc(256 * 16);    // 4 KB
  float* zp       = (float*)alloc(64 * 4);         // zero page for OOB DMA
  (void)ws_size;

  const int BS = 256;
  const int SB = (n + 1023) / 1024;  // scan blocks (98 for n=100k, <=128)
  const int GB = (n + 127) / 128;    // gemm blocks (512 thr, 128 rows)

  // ---- setup: weight prepack + zero counts + zero page ----
  k_setup<<<25 + (n + 255) / 256, 256, 0, stream>>>(
      Wi, Wg1, Wg2, Wg3, pWi, pWg1, pWg2, pWg3, counts, zp, n);

  // ---- CSR build (shared by all three convs) ----
  k_count<<<(e + BS - 1) / BS, BS, 0, stream>>>(dst, counts, e);
  k_scan_part<<<SB, 256, 0, stream>>>(counts, bsums, n);
  k_scan_top<<<1, 128, 0, stream>>>(bsums, SB);
  k_scan_down<<<SB, 256, 0, stream>>>(counts, bsums, offsets, dinv, n, e);
  k_fill<<<(e + BS - 1) / BS, BS, 0, stream>>>(src, dst, offsets, counts, dinv,
                                               csr, e);

  // ---- input layer: A = h = LN(relu(x@Wi+bi))  [fp16] ----
  k_gemm_in<<<GB, 512, 0, stream>>>(x, pWi, bi, g1, b1, zp, A, n);

  // ---- conv1: B = xw1 = h@Wg1; gather -> C = h1 = relu(agg)+h ----
  k_gemm_f16<128, 128><<<GB, 512, 0, stream>>>(A, pWg1, zp, B, n);
  k_gather<128, 0><<<(n + 7) / 8, 256, 0, stream>>>(
      offsets, csr, B, dinv, bg1, A, nullptr, nullptr, C, n);

  // ---- conv2: A = xw2 = h1@Wg2 [n,64]; gather -> B = h2 = LN(relu(agg)) ----
  k_gemm_f16<128, 64><<<GB, 512, 0, stream>>>(C, pWg2, zp, A, n);
  k_gather<64, 1><<<(n + 15) / 16, 256, 0, stream>>>(
      offsets, csr, A, dinv, bg2, nullptr, g2, b2, B, n);

  // ---- conv3: A = xw3 = h2@Wg3 [n,32]; gather -> C = agg3 [fp16] ----
  k_gemm_f16<64, 32><<<GB, 512, 0, stream>>>(B, pWg3, zp, A, n);
  k_gather<32, 2><<<(n + 31) / 32, 256, 0, stream>>>(
      offsets, csr, A, dinv, bg3, nullptr, nullptr, nullptr, C, n);

  // ---- tail: relu(agg3) -> MHA(v,o) -> MLP -> out ----
  k_tail<<<(n + BS - 1) / BS, BS, 0, stream>>>(
      C, Wv, bv, Wo, bo, Wc1, bc1, Wc2, bc2, Wc3, bc3, (float*)d_out, n);
}

// Round 12
// 219.070 us; speedup vs baseline: 1.0820x; 1.0382x over previous
//
#include <hip/hip_runtime.h>

// ---------------------------------------------------------------------------
// EnhancedBitcoinGCN: 3x GCNConv + LN/residual + (trivial) MHA + MLP head
// Round 11 -> 12 (store-path round):
//  * Decisive evidence: rocprof replays with x fully L3-resident (FETCH~0)
//    still take 44us -> k_gemm_in was never load-bound. The one thing all
//    six prior structures shared: 32 scattered 2B stores per lane (four 32B
//    segments per wave-store instruction).
//  * Fix: repack D-fragments through wave-private LDS (no barriers) and
//    store row-contiguous f16x8 (1KB per wave-store). Applied to all GEMMs.
//  * k_gemm_in drops the x lo-term (hi-only fp16, like conv weights):
//    halves the MFMA+cvt chain. absmax est <= 0.06 (threshold 0.13).
//  * conv3 gather + tail fused into k_gt (kills 12.8MB round-trip + launch).
//  * scan_top folded into scan_down. Launches 14 -> 12.
// ---------------------------------------------------------------------------

typedef __attribute__((ext_vector_type(8))) _Float16 f16x8;
typedef __attribute__((ext_vector_type(4))) _Float16 f16x4;
typedef __attribute__((ext_vector_type(4))) float f32x4;

#define GLOAD_LDS16(gp, lp)                                        \
  __builtin_amdgcn_global_load_lds(                                \
      (const __attribute__((address_space(1))) void*)(gp),         \
      (__attribute__((address_space(3))) void*)(lp), 16, 0, 0)

static __device__ __forceinline__ void wait_vm0() {
  asm volatile("s_waitcnt vmcnt(0)" ::: "memory");
}
static __device__ __forceinline__ void wait_vm1() {
  asm volatile("s_waitcnt vmcnt(1)" ::: "memory");
}
static __device__ __forceinline__ void wait_vm2() {
  asm volatile("s_waitcnt vmcnt(2)" ::: "memory");
}
static __device__ __forceinline__ void wait_lgkm0() {
  asm volatile("s_waitcnt lgkmcnt(0)" ::: "memory");
  __builtin_amdgcn_sched_barrier(0);
}

// ---------------- CSR build ----------------
__global__ void k_count(const int* __restrict__ dst, int* __restrict__ counts, int e) {
  int i = blockIdx.x * blockDim.x + threadIdx.x;
  if (i < e) atomicAdd(&counts[dst[i]], 1);
}

__global__ __launch_bounds__(256) void k_scan_part(
    const int* __restrict__ counts, int* __restrict__ bsums, int n) {
  int tid = threadIdx.x;
  int i0 = blockIdx.x * 1024 + tid * 4;
  int s = 0;
#pragma unroll
  for (int k = 0; k < 4; k++) { int i = i0 + k; if (i < n) s += counts[i]; }
#pragma unroll
  for (int d = 1; d < 64; d <<= 1) s += __shfl_xor(s, d);
  __shared__ int wsum[4];
  int lane = tid & 63, w = tid >> 6;
  if (lane == 0) wsum[w] = s;
  __syncthreads();
  if (tid == 0) bsums[blockIdx.x] = wsum[0] + wsum[1] + wsum[2] + wsum[3];
}

// offsets + dinv + (counts -> 0, becoming fill cursor). Each block computes
// its own prefix over bsums (folds the old scan_top kernel).
__global__ __launch_bounds__(256) void k_scan_down(
    int* __restrict__ counts, const int* __restrict__ bsums,
    int* __restrict__ offsets, float* __restrict__ dinv, int n, int e, int nb) {
  int tid = threadIdx.x;
  int lane = tid & 63, w = tid >> 6;
  __shared__ int wsum[4], psum[4];
  // block prefix: sum of bsums[t] for t < blockIdx.x
  int pv = (tid < nb && tid < blockIdx.x) ? bsums[tid] : 0;
#pragma unroll
  for (int d = 1; d < 64; d <<= 1) pv += __shfl_xor(pv, d);
  if (lane == 0) psum[w] = pv;
  __syncthreads();
  int blockpref = psum[0] + psum[1] + psum[2] + psum[3];

  int i0 = blockIdx.x * 1024 + tid * 4;
  int c[4]; int tsum = 0;
#pragma unroll
  for (int k = 0; k < 4; k++) { int i = i0 + k; c[k] = (i < n) ? counts[i] : 0; tsum += c[k]; }
  int v = tsum;
#pragma unroll
  for (int d = 1; d < 64; d <<= 1) { int t = __shfl_up(v, d); if (lane >= d) v += t; }
  if (lane == 63) wsum[w] = v;
  __syncthreads();
  int wadd = 0;
#pragma unroll
  for (int q = 0; q < 4; q++) if (q < w) wadd += wsum[q];
  int run = (v - tsum) + wadd + blockpref;
#pragma unroll
  for (int k = 0; k < 4; k++) {
    int i = i0 + k;
    if (i < n) {
      offsets[i] = run;
      dinv[i] = rsqrtf((float)(c[k] + 1));
      counts[i] = 0;  // becomes fill cursor
    }
    run += c[k];
  }
  if (blockIdx.x == 0 && tid == 0) offsets[n] = e;
}

// packed edge record: {src, norm as bits}
__global__ void k_fill(const int* __restrict__ src, const int* __restrict__ dst,
                       const int* __restrict__ offsets, int* __restrict__ cursor,
                       const float* __restrict__ dinv, int2* __restrict__ csr, int e) {
  int i = blockIdx.x * blockDim.x + threadIdx.x;
  if (i >= e) return;
  int s = src[i], d = dst[i];
  int pos = atomicAdd(&cursor[d], 1);
  csr[offsets[d] + pos] = make_int2(s, __float_as_int(dinv[s] * dinv[d]));
}

// ---------------- weight prepack (fragment-ordered fp16, hi only) ----------
__device__ __forceinline__ void pack_hi(const float* __restrict__ W,
                                        _Float16* __restrict__ dst,
                                        int K, int N, int u) {
  int lane = u & 63; int rest = u >> 6; int CT = N >> 4;
  int ct = rest % CT, ks = rest / CT;
  int gcol = ct * 16 + (lane & 15);
  int gk0 = ks * 32 + (lane >> 4) * 8;
  size_t o = (size_t)(ks * CT + ct) * 512 + lane * 8;
#pragma unroll
  for (int i = 0; i < 8; i++) {
    float v = (gk0 + i < K) ? W[(size_t)(gk0 + i) * N + gcol] : 0.0f;
    dst[o + i] = (_Float16)v;
  }
}

__global__ void k_setup(const float* __restrict__ Wi, const float* __restrict__ Wg1,
                        const float* __restrict__ Wg2, const float* __restrict__ Wg3,
                        _Float16* __restrict__ pWi, _Float16* __restrict__ pWg1,
                        _Float16* __restrict__ pWg2, _Float16* __restrict__ pWg3,
                        int* __restrict__ counts, float* __restrict__ zp, int n) {
  int b = blockIdx.x;
  if (b < 25) {
    int t = b * 256 + threadIdx.x;
    if (t < 3072) pack_hi(Wi, pWi, 164, 128, t);
    else if (t < 5120) pack_hi(Wg1, pWg1, 128, 128, t - 3072);
    else if (t < 6144) pack_hi(Wg2, pWg2, 128, 64, t - 5120);
    else if (t < 6400) pack_hi(Wg3, pWg3, 64, 32, t - 6144);
  } else {
    if (b == 25 && threadIdx.x < 64) zp[threadIdx.x] = 0.0f;
    int i = (b - 25) * 256 + threadIdx.x;
    if (i < n) counts[i] = 0;
  }
}

// ---------------- input GEMM: h = LN(relu(x@Wi+bi)) ----------------
// Barrier-free wave-private DMA pipeline (r11) + hi-only x + LDS-repacked
// coalesced f16x8 stores.
__global__ __launch_bounds__(512, 4) void k_gemm_in(
    const float* __restrict__ x, const _Float16* __restrict__ pB,
    const float* __restrict__ bias, const float* __restrict__ gamma,
    const float* __restrict__ beta, const float* __restrict__ zp,
    _Float16* __restrict__ out, int n) {
  constexpr int N = 128, CT = 8;
  __shared__ __align__(16) float sAi[8][2][512];  // 8 waves x 2 bufs x 2KB
  int tid = threadIdx.x;
  int lane = tid & 63, w = tid >> 6;
  int rowbase = blockIdx.x * 128 + w * 16;
  const f16x8* Bf = (const f16x8*)pB;

  auto stage = [&](int ks, int buf) {
#pragma unroll
    for (int j = 0; j < 2; j++) {
      int r_ = j * 8 + (lane >> 3);
      int c_ = (lane & 7) ^ (lane >> 3);      // swizzled source chunk
      int rg = rowbase + r_;
      bool ok = (rg < n) && (ks < 5 || c_ == 0);
      const void* s = ok ? (const void*)(x + (size_t)rg * 164 + ks * 32 + c_ * 4)
                         : (const void*)zp;
      GLOAD_LDS16(s, &sAi[w][buf][j * 256]);
    }
  };

  f32x4 acc[CT];
#pragma unroll
  for (int c = 0; c < CT; c++) acc[c] = (f32x4)0.0f;

  int rr = lane & 15;
  int c0 = (lane >> 4) * 2;
  int s0 = c0 ^ (rr & 7);
  int s1 = (c0 + 1) ^ (rr & 7);

  stage(0, 0);
#pragma unroll
  for (int ks = 0; ks < 6; ks++) {
    f16x8 bfr[CT];
#pragma unroll
    for (int c = 0; c < CT; c++) bfr[c] = Bf[(ks * CT + c) * 64 + lane];
    if (ks + 1 < 6) { stage(ks + 1, (ks + 1) & 1); wait_vm2(); }
    else wait_vm0();
    const float* bp = &sAi[w][ks & 1][0];
    float4 u0 = *(const float4*)&bp[rr * 32 + s0 * 4];
    float4 u1 = *(const float4*)&bp[rr * 32 + s1 * 4];
    float v[8] = {u0.x, u0.y, u0.z, u0.w, u1.x, u1.y, u1.z, u1.w};
    f16x8 ah;
#pragma unroll
    for (int i = 0; i < 8; i++) ah[i] = (_Float16)v[i];
#pragma unroll
    for (int c = 0; c < CT; c++)
      acc[c] = __builtin_amdgcn_mfma_f32_16x16x32_f16(ah, bfr[c], acc[c], 0, 0, 0);
  }

  // bias + relu + LN over N cols (row lives in a 16-lane group; wave-local)
  int r0 = (lane >> 4) * 4;
  int li = lane & 15;
  float s1v[4] = {0, 0, 0, 0}, s2v[4] = {0, 0, 0, 0};
#pragma unroll
  for (int c = 0; c < CT; c++) {
    float bb = bias[c * 16 + li];
#pragma unroll
    for (int r = 0; r < 4; r++) {
      float t = acc[c][r] + bb;
      t = t > 0.0f ? t : 0.0f;
      acc[c][r] = t;
      s1v[r] += t;
      s2v[r] += t * t;
    }
  }
#pragma unroll
  for (int m = 1; m < 16; m <<= 1) {
#pragma unroll
    for (int r = 0; r < 4; r++) {
      s1v[r] += __shfl_xor(s1v[r], m);
      s2v[r] += __shfl_xor(s2v[r], m);
    }
  }
  // repack through wave-private LDS (reuse staging: 4KB/wave) -> f16x8 stores
  wait_lgkm0();
  _Float16* lr = (_Float16*)&sAi[w][0][0];  // 16 rows x 128 f16 = 4KB
#pragma unroll
  for (int c = 0; c < CT; c++) {
    float gv = gamma[c * 16 + li], bv = beta[c * 16 + li];
#pragma unroll
    for (int r = 0; r < 4; r++) {
      float mean = s1v[r] * (1.0f / N);
      float var = s2v[r] * (1.0f / N) - mean * mean;
      float rs = rsqrtf(var + 1e-5f);
      lr[(r0 + r) * 128 + c * 16 + li] =
          (_Float16)((acc[c][r] - mean) * rs * gv + bv);
    }
  }
  wait_lgkm0();
#pragma unroll
  for (int i = 0; i < 4; i++) {
    int chunk = i * 64 + lane;          // 256 chunks = 16 rows x 16
    int rloc = chunk >> 4;
    int cc = chunk & 15;
    if (rowbase + rloc < n)
      *(f16x8*)&out[(size_t)(rowbase + rloc) * 128 + cc * 8] =
          *(const f16x8*)&lr[chunk * 8];
  }
}

// ---------------- conv GEMM: xw = A@W (fp16 x fp16-hi) ---------------------
template <int K, int N>
__global__ __launch_bounds__(512, 4) void k_gemm_f16(
    const _Float16* __restrict__ A, const _Float16* __restrict__ pB,
    const float* __restrict__ zp, _Float16* __restrict__ out, int n) {
  constexpr int KS = K / 32, CT = N / 16;
  __shared__ __align__(16) _Float16 sA[8][2][512];  // staging 16KB
  __shared__ __align__(16) _Float16 sR[8][16 * N];  // repack 16*N f16 / wave
  int tid = threadIdx.x;
  int lane = tid & 63, w = tid >> 6;
  int rowbase = blockIdx.x * 128 + w * 16;
  const f16x8* Bf = (const f16x8*)pB;

  int r_ = lane >> 2;
  int c_ = (lane & 3) ^ (r_ & 3);
  int rg = rowbase + r_;
  const _Float16* asrc = A + (size_t)rg * K + c_ * 8;
  bool rok = rg < n;

  auto stage = [&](int ks, int buf) {
    const void* s = rok ? (const void*)(asrc + ks * 32) : (const void*)zp;
    GLOAD_LDS16(s, &sA[w][buf][0]);
  };

  f32x4 acc[CT];
#pragma unroll
  for (int c = 0; c < CT; c++) acc[c] = (f32x4)0.0f;

  int rr = lane & 15;
  int slot = (lane >> 4) ^ (rr & 3);

  stage(0, 0);
#pragma unroll
  for (int ks = 0; ks < KS; ks++) {
    f16x8 bfr[CT];
#pragma unroll
    for (int c = 0; c < CT; c++) bfr[c] = Bf[(ks * CT + c) * 64 + lane];
    if (ks + 1 < KS) { stage(ks + 1, (ks + 1) & 1); wait_vm1(); }
    else wait_vm0();
    f16x8 av = *(const f16x8*)&sA[w][ks & 1][rr * 32 + slot * 8];
#pragma unroll
    for (int c = 0; c < CT; c++)
      acc[c] = __builtin_amdgcn_mfma_f32_16x16x32_f16(av, bfr[c], acc[c], 0, 0, 0);
  }

  int r0 = (lane >> 4) * 4;
  int li = lane & 15;
  wait_lgkm0();
  _Float16* lr = &sR[w][0];
#pragma unroll
  for (int c = 0; c < CT; c++) {
#pragma unroll
    for (int r = 0; r < 4; r++)
      lr[(r0 + r) * N + c * 16 + li] = (_Float16)acc[c][r];
  }
  wait_lgkm0();
#pragma unroll
  for (int i = 0; i < N / 32; i++) {
    int chunk = i * 64 + lane;          // 2N chunks = 16 rows x N/8
    int rloc = chunk / (N / 8);
    int cc = chunk % (N / 8);
    if (rowbase + rloc < n)
      *(f16x8*)&out[(size_t)(rowbase + rloc) * N + cc * 8] =
          *(const f16x8*)&lr[chunk * 8];
  }
}

// ---------------- dst-side gather, 4 cols/thread, 8-deep load batches ------
// MODE 0: out = relu(agg) + auxh[node]      (conv1)
// MODE 1: out = LN(relu(agg); gamma, beta)  (conv2)
template <int OUT_D, int MODE>
__global__ __launch_bounds__(256, 2) void k_gather(
    const int* __restrict__ off, const int2* __restrict__ csr,
    const _Float16* __restrict__ xw, const float* __restrict__ dinv,
    const float* __restrict__ bias, const _Float16* __restrict__ auxh,
    const float* __restrict__ gamma, const float* __restrict__ beta,
    _Float16* __restrict__ out, int n) {
  constexpr int TPN = OUT_D / 4;
  constexpr int NPB = 256 / TPN;
  int tid = threadIdx.x;
  int node = blockIdx.x * NPB + tid / TPN;
  int li = tid % TPN;
  if (node >= n) return;
  int start = off[node], end = off[node + 1];
  float di = dinv[node];
  float d2 = di * di;
  const _Float16* xp = xw + 4 * li;
  f16x4 self = *(const f16x4*)(xp + (size_t)node * OUT_D);
  f16x4 hres;
  if constexpr (MODE == 0)
    hres = *(const f16x4*)(auxh + (size_t)node * OUT_D + 4 * li);
  float a0 = (float)self[0] * d2 + bias[4 * li + 0];
  float a1 = (float)self[1] * d2 + bias[4 * li + 1];
  float a2 = (float)self[2] * d2 + bias[4 * li + 2];
  float a3 = (float)self[3] * d2 + bias[4 * li + 3];
  for (int cb = start; cb < end; cb += TPN) {
    int m = end - cb; if (m > TPN) m = TPN;
    int sv = node; float nv = 0.0f;
    if (li < m) { int2 me = csr[cb + li]; sv = me.x; nv = __int_as_float(me.y); }
    for (int j0 = 0; j0 < m; j0 += 8) {
      int s0 = __shfl(sv, j0 + 0, TPN), s1 = __shfl(sv, j0 + 1, TPN);
      int s2 = __shfl(sv, j0 + 2, TPN), s3 = __shfl(sv, j0 + 3, TPN);
      int s4 = __shfl(sv, j0 + 4, TPN), s5 = __shfl(sv, j0 + 5, TPN);
      int s6 = __shfl(sv, j0 + 6, TPN), s7 = __shfl(sv, j0 + 7, TPN);
      float w0 = __shfl(nv, j0 + 0, TPN), w1 = __shfl(nv, j0 + 1, TPN);
      float w2 = __shfl(nv, j0 + 2, TPN), w3 = __shfl(nv, j0 + 3, TPN);
      float w4 = __shfl(nv, j0 + 4, TPN), w5 = __shfl(nv, j0 + 5, TPN);
      float w6 = __shfl(nv, j0 + 6, TPN), w7 = __shfl(nv, j0 + 7, TPN);
      f16x4 v0 = *(const f16x4*)(xp + (size_t)s0 * OUT_D);
      f16x4 v1 = *(const f16x4*)(xp + (size_t)s1 * OUT_D);
      f16x4 v2 = *(const f16x4*)(xp + (size_t)s2 * OUT_D);
      f16x4 v3 = *(const f16x4*)(xp + (size_t)s3 * OUT_D);
      f16x4 v4 = *(const f16x4*)(xp + (size_t)s4 * OUT_D);
      f16x4 v5 = *(const f16x4*)(xp + (size_t)s5 * OUT_D);
      f16x4 v6 = *(const f16x4*)(xp + (size_t)s6 * OUT_D);
      f16x4 v7 = *(const f16x4*)(xp + (size_t)s7 * OUT_D);
      a0 += (float)v0[0] * w0 + (float)v1[0] * w1 + (float)v2[0] * w2 + (float)v3[0] * w3
          + (float)v4[0] * w4 + (float)v5[0] * w5 + (float)v6[0] * w6 + (float)v7[0] * w7;
      a1 += (float)v0[1] * w0 + (float)v1[1] * w1 + (float)v2[1] * w2 + (float)v3[1] * w3
          + (float)v4[1] * w4 + (float)v5[1] * w5 + (float)v6[1] * w6 + (float)v7[1] * w7;
      a2 += (float)v0[2] * w0 + (float)v1[2] * w1 + (float)v2[2] * w2 + (float)v3[2] * w3
          + (float)v4[2] * w4 + (float)v5[2] * w5 + (float)v6[2] * w6 + (float)v7[2] * w7;
      a3 += (float)v0[3] * w0 + (float)v1[3] * w1 + (float)v2[3] * w2 + (float)v3[3] * w3
          + (float)v4[3] * w4 + (float)v5[3] * w5 + (float)v6[3] * w6 + (float)v7[3] * w7;
    }
  }
  _Float16* po = out + (size_t)node * OUT_D + 4 * li;
  if constexpr (MODE == 0) {
    f16x4 o;
    o[0] = (_Float16)((a0 > 0.0f ? a0 : 0.0f) + (float)hres[0]);
    o[1] = (_Float16)((a1 > 0.0f ? a1 : 0.0f) + (float)hres[1]);
    o[2] = (_Float16)((a2 > 0.0f ? a2 : 0.0f) + (float)hres[2]);
    o[3] = (_Float16)((a3 > 0.0f ? a3 : 0.0f) + (float)hres[3]);
    *(f16x4*)po = o;
  } else {
    float v0 = a0 > 0.0f ? a0 : 0.0f, v1 = a1 > 0.0f ? a1 : 0.0f;
    float v2 = a2 > 0.0f ? a2 : 0.0f, v3 = a3 > 0.0f ? a3 : 0.0f;
    float s1 = v0 + v1 + v2 + v3;
    float s2 = v0 * v0 + v1 * v1 + v2 * v2 + v3 * v3;
#pragma unroll
    for (int d = 1; d < TPN; d <<= 1) {
      s1 += __shfl_xor(s1, d, TPN);
      s2 += __shfl_xor(s2, d, TPN);
    }
    float m_ = s1 * (1.0f / OUT_D);
    float var = s2 * (1.0f / OUT_D) - m_ * m_;
    float rs = rsqrtf(var + 1e-5f);
    f16x4 o;
    o[0] = (_Float16)((v0 - m_) * rs * gamma[4 * li + 0] + beta[4 * li + 0]);
    o[1] = (_Float16)((v1 - m_) * rs * gamma[4 * li + 1] + beta[4 * li + 1]);
    o[2] = (_Float16)((v2 - m_) * rs * gamma[4 * li + 2] + beta[4 * li + 2]);
    o[3] = (_Float16)((v3 - m_) * rs * gamma[4 * li + 3] + beta[4 * li + 3]);
    *(f16x4*)po = o;
  }
}

// ---------------- fused conv3 gather + tail --------------------------------
// Phase 1: 8 sub-batches of 32 nodes, 8 thr/node gather agg3 -> padded LDS.
// Phase 2: one node per thread: relu -> Wv -> Wo -> Wc1 -> Wc2 -> Wc3.
__global__ __launch_bounds__(256, 2) void k_gt(
    const int* __restrict__ off, const int2* __restrict__ csr,
    const _Float16* __restrict__ xw, const float* __restrict__ dinv,
    const float* __restrict__ bg3, const float* __restrict__ Wv,
    const float* __restrict__ bv, const float* __restrict__ Wo,
    const float* __restrict__ bo, const float* __restrict__ Wc1,
    const float* __restrict__ bc1, const float* __restrict__ Wc2,
    const float* __restrict__ bc2, const float* __restrict__ Wc3,
    const float* __restrict__ bc3, float* __restrict__ out, int n) {
  __shared__ float sAgg[256][33];  // padded: tail reads stride 33 (no bank dup)
  __shared__ float sWv[1024], sWo[1024], sWc1[512], sWc2[512];
  __shared__ float sbv[32], sbo[32], sbc2[32], sWc3[32], sbc1[16], sbc3[1];
  int tid = threadIdx.x;
  for (int i = tid; i < 1024; i += 256) { sWv[i] = Wv[i]; sWo[i] = Wo[i]; }
  for (int i = tid; i < 512; i += 256) { sWc1[i] = Wc1[i]; sWc2[i] = Wc2[i]; }
  if (tid < 32) { sbv[tid] = bv[tid]; sbo[tid] = bo[tid];
                  sbc2[tid] = bc2[tid]; sWc3[tid] = Wc3[tid]; }
  if (tid < 16) sbc1[tid] = bc1[tid];
  if (tid == 0) sbc3[0] = bc3[0];

  int base0 = blockIdx.x * 256;
  int li = tid & 7;
  const _Float16* xp = xw + 4 * li;
  for (int sub = 0; sub < 8; sub++) {
    int nl = sub * 32 + (tid >> 3);
    int node = base0 + nl;
    if (node < n) {
      int start = off[node], end = off[node + 1];
      float di = dinv[node];
      float d2 = di * di;
      f16x4 self = *(const f16x4*)(xp + (size_t)node * 32);
      float a0 = (float)self[0] * d2 + bg3[4 * li + 0];
      float a1 = (float)self[1] * d2 + bg3[4 * li + 1];
      float a2 = (float)self[2] * d2 + bg3[4 * li + 2];
      float a3 = (float)self[3] * d2 + bg3[4 * li + 3];
      for (int cb = start; cb < end; cb += 8) {
        int m = end - cb; if (m > 8) m = 8;
        int sv = node; float nv = 0.0f;
        if (li < m) { int2 me = csr[cb + li]; sv = me.x; nv = __int_as_float(me.y); }
        for (int j0 = 0; j0 < m; j0 += 8) {
          int s0 = __shfl(sv, j0 + 0, 8), s1 = __shfl(sv, j0 + 1, 8);
          int s2 = __shfl(sv, j0 + 2, 8), s3 = __shfl(sv, j0 + 3, 8);
          int s4 = __shfl(sv, j0 + 4, 8), s5 = __shfl(sv, j0 + 5, 8);
          int s6 = __shfl(sv, j0 + 6, 8), s7 = __shfl(sv, j0 + 7, 8);
          float w0 = __shfl(nv, j0 + 0, 8), w1 = __shfl(nv, j0 + 1, 8);
          float w2 = __shfl(nv, j0 + 2, 8), w3 = __shfl(nv, j0 + 3, 8);
          float w4 = __shfl(nv, j0 + 4, 8), w5 = __shfl(nv, j0 + 5, 8);
          float w6 = __shfl(nv, j0 + 6, 8), w7 = __shfl(nv, j0 + 7, 8);
          f16x4 v0 = *(const f16x4*)(xp + (size_t)s0 * 32);
          f16x4 v1 = *(const f16x4*)(xp + (size_t)s1 * 32);
          f16x4 v2 = *(const f16x4*)(xp + (size_t)s2 * 32);
          f16x4 v3 = *(const f16x4*)(xp + (size_t)s3 * 32);
          f16x4 v4 = *(const f16x4*)(xp + (size_t)s4 * 32);
          f16x4 v5 = *(const f16x4*)(xp + (size_t)s5 * 32);
          f16x4 v6 = *(const f16x4*)(xp + (size_t)s6 * 32);
          f16x4 v7 = *(const f16x4*)(xp + (size_t)s7 * 32);
          a0 += (float)v0[0] * w0 + (float)v1[0] * w1 + (float)v2[0] * w2 + (float)v3[0] * w3
              + (float)v4[0] * w4 + (float)v5[0] * w5 + (float)v6[0] * w6 + (float)v7[0] * w7;
          a1 += (float)v0[1] * w0 + (float)v1[1] * w1 + (float)v2[1] * w2 + (float)v3[1] * w3
              + (float)v4[1] * w4 + (float)v5[1] * w5 + (float)v6[1] * w6 + (float)v7[1] * w7;
          a2 += (float)v0[2] * w0 + (float)v1[2] * w1 + (float)v2[2] * w2 + (float)v3[2] * w3
              + (float)v4[2] * w4 + (float)v5[2] * w5 + (float)v6[2] * w6 + (float)v7[2] * w7;
          a3 += (float)v0[3] * w0 + (float)v1[3] * w1 + (float)v2[3] * w2 + (float)v3[3] * w3
              + (float)v4[3] * w4 + (float)v5[3] * w5 + (float)v6[3] * w6 + (float)v7[3] * w7;
        }
      }
      float* dst = &sAgg[nl][4 * li];
      dst[0] = a0; dst[1] = a1; dst[2] = a2; dst[3] = a3;
    }
  }
  __syncthreads();
  int node = base0 + tid;
  if (node >= n) return;
  float a[32];
#pragma unroll
  for (int j = 0; j < 32; j++) {
    float f = sAgg[tid][j];
    a[j] = f > 0.0f ? f : 0.0f;
  }
  float v[32];
#pragma unroll
  for (int j = 0; j < 32; j++) v[j] = sbv[j];
  for (int k = 0; k < 32; k++) {
#pragma unroll
    for (int j = 0; j < 32; j++) v[j] += a[k] * sWv[k * 32 + j];
  }
  float o[32];
#pragma unroll
  for (int j = 0; j < 32; j++) o[j] = sbo[j];
  for (int k = 0; k < 32; k++) {
#pragma unroll
    for (int j = 0; j < 32; j++) o[j] += v[k] * sWo[k * 32 + j];
  }
  float c1[16];
#pragma unroll
  for (int j = 0; j < 16; j++) c1[j] = sbc1[j];
  for (int k = 0; k < 32; k++) {
#pragma unroll
    for (int j = 0; j < 16; j++) c1[j] += o[k] * sWc1[k * 16 + j];
  }
#pragma unroll
  for (int j = 0; j < 16; j++) c1[j] = c1[j] > 0.0f ? c1[j] : 0.0f;
  float c2[32];
#pragma unroll
  for (int j = 0; j < 32; j++) c2[j] = sbc2[j];
  for (int k = 0; k < 16; k++) {
#pragma unroll
    for (int j = 0; j < 32; j++) c2[j] += c1[k] * sWc2[k * 32 + j];
  }
  float r = sbc3[0];
#pragma unroll
  for (int k = 0; k < 32; k++) {
    float c = c2[k] > 0.0f ? c2[k] : 0.0f;
    r += c * sWc3[k];
  }
  out[node] = r;
}

// ---------------------------------------------------------------------------
extern "C" void kernel_launch(void* const* d_in, const int* in_sizes, int n_in,
                              void* d_out, int out_size, void* d_ws, size_t ws_size,
                              hipStream_t stream) {
  const float* x   = (const float*)d_in[0];
  const int* ei    = (const int*)d_in[1];
  const float* Wi  = (const float*)d_in[2];
  const float* bi  = (const float*)d_in[3];
  const float* g1  = (const float*)d_in[4];
  const float* b1  = (const float*)d_in[5];
  const float* Wg1 = (const float*)d_in[6];
  const float* bg1 = (const float*)d_in[7];
  const float* Wg2 = (const float*)d_in[8];
  const float* bg2 = (const float*)d_in[9];
  const float* g2  = (const float*)d_in[10];
  const float* b2  = (const float*)d_in[11];
  const float* Wg3 = (const float*)d_in[12];
  const float* bg3 = (const float*)d_in[13];
  // d_in[14..17]: Wq,bq,Wk,bk — mathematically dead (softmax over 1 key == 1)
  const float* Wv  = (const float*)d_in[18];
  const float* bv  = (const float*)d_in[19];
  const float* Wo  = (const float*)d_in[20];
  const float* bo  = (const float*)d_in[21];
  const float* Wc1 = (const float*)d_in[22];
  const float* bc1 = (const float*)d_in[23];
  const float* Wc2 = (const float*)d_in[24];
  const float* bc2 = (const float*)d_in[25];
  const float* Wc3 = (const float*)d_in[26];
  const float* bc3 = (const float*)d_in[27];

  const int n = in_sizes[0] / 164;
  const int e = in_sizes[1] / 2;
  const int* src = ei;
  const int* dst = ei + e;

  // workspace layout (256B aligned)
  char* ws = (char*)d_ws;
  size_t off = 0;
  auto alloc = [&](size_t bytes) {
    char* p = ws + off;
    off += (bytes + 255) & ~(size_t)255;
    return p;
  };
  _Float16* A     = (_Float16*)alloc((size_t)n * 128 * 2);
  _Float16* B     = (_Float16*)alloc((size_t)n * 128 * 2);
  _Float16* C     = (_Float16*)alloc((size_t)n * 128 * 2);
  float* dinv     = (float*)alloc((size_t)n * 4);
  int*   counts   = (int*)alloc((size_t)n * 4);      // reused as fill cursor
  int*   offsets  = (int*)alloc((size_t)(n + 1) * 4);
  int*   bsums    = (int*)alloc(256 * 4);
  int2*  csr      = (int2*)alloc((size_t)e * 8);
  _Float16* pWi   = (_Float16*)alloc(3072 * 16);   // 48 KB
  _Float16* pWg1  = (_Float16*)alloc(2048 * 16);   // 32 KB
  _Float16* pWg2  = (_Float16*)alloc(1024 * 16);   // 16 KB
  _Float16* pWg3  = (_Float16*)alloc(256 * 16);    // 4 KB
  float* zp       = (float*)alloc(64 * 4);         // zero page for OOB DMA
  (void)ws_size;

  const int BS = 256;
  const int SB = (n + 1023) / 1024;  // scan blocks (98 for n=100k, <=256)
  const int GB = (n + 127) / 128;    // gemm blocks (512 thr, 128 rows)

  // ---- setup: weight prepack + zero counts + zero page ----
  k_setup<<<25 + (n + 255) / 256, 256, 0, stream>>>(
      Wi, Wg1, Wg2, Wg3, pWi, pWg1, pWg2, pWg3, counts, zp, n);

  // ---- CSR build (shared by all three convs) ----
  k_count<<<(e + BS - 1) / BS, BS, 0, stream>>>(dst, counts, e);
  k_scan_part<<<SB, 256, 0, stream>>>(counts, bsums, n);
  k_scan_down<<<SB, 256, 0, stream>>>(counts, bsums, offsets, dinv, n, e, SB);
  k_fill<<<(e + BS - 1) / BS, BS, 0, stream>>>(src, dst, offsets, counts, dinv,
                                               csr, e);

  // ---- input layer: A = h = LN(relu(x@Wi+bi))  [fp16] ----
  k_gemm_in<<<GB, 512, 0, stream>>>(x, pWi, bi, g1, b1, zp, A, n);

  // ---- conv1: B = xw1 = h@Wg1; gather -> C = h1 = relu(agg)+h ----
  k_gemm_f16<128, 128><<<GB, 512, 0, stream>>>(A, pWg1, zp, B, n);
  k_gather<128, 0><<<(n + 7) / 8, 256, 0, stream>>>(
      offsets, csr, B, dinv, bg1, A, nullptr, nullptr, C, n);

  // ---- conv2: A = xw2 = h1@Wg2 [n,64]; gather -> B = h2 = LN(relu(agg)) ----
  k_gemm_f16<128, 64><<<GB, 512, 0, stream>>>(C, pWg2, zp, A, n);
  k_gather<64, 1><<<(n + 15) / 16, 256, 0, stream>>>(
      offsets, csr, A, dinv, bg2, nullptr, g2, b2, B, n);

  // ---- conv3: A = xw3 = h2@Wg3 [n,32]; fused gather+tail -> out ----
  k_gemm_f16<64, 32><<<GB, 512, 0, stream>>>(B, pWg3, zp, A, n);
  k_gt<<<(n + 255) / 256, 256, 0, stream>>>(
      offsets, csr, A, dinv, bg3, Wv, bv, Wo, bo, Wc1, bc1, Wc2, bc2,
      Wc3, bc3, (float*)d_out, n);
}

// Round 13
// 213.758 us; speedup vs baseline: 1.1089x; 1.0249x over previous
//
#include <hip/hip_runtime.h>

// ---------------------------------------------------------------------------
// EnhancedBitcoinGCN: 3x GCNConv + LN/residual + (trivial) MHA + MLP head
// Round 12 -> 13:
//  * UN-FUSE k_gt (42us @ 13% occupancy: 391-block grid + 8 serial
//    sub-batches was a regression) back to k_gather<32,2> + k_tail.
//  * GEMMs: register-double-buffered B prefetch. Iteration ks issues
//    B(ks+1) (8 loads) + DMA(ks+1) (A-tile), then waits vmcnt(10): in-order
//    retirement drains exactly B(ks)+DMA(ks) issued LAST iteration, leaving
//    the 10 newest in flight -> neither A nor B latency is ever on the
//    same-iteration critical path (the flaw shared by all prior rounds).
//    asm "memory" waits pin the issue order against compiler sinking.
//  * Keep r12's LDS-repacked coalesced f16x8 stores + hi-only fp16 weights.
// ---------------------------------------------------------------------------

typedef __attribute__((ext_vector_type(8))) _Float16 f16x8;
typedef __attribute__((ext_vector_type(4))) _Float16 f16x4;
typedef __attribute__((ext_vector_type(4))) float f32x4;

#define GLOAD_LDS16(gp, lp)                                        \
  __builtin_amdgcn_global_load_lds(                                \
      (const __attribute__((address_space(1))) void*)(gp),         \
      (__attribute__((address_space(3))) void*)(lp), 16, 0, 0)

static __device__ __forceinline__ void wait_vm0() {
  asm volatile("s_waitcnt vmcnt(0)" ::: "memory");
}
static __device__ __forceinline__ void wait_vm10() {
  asm volatile("s_waitcnt vmcnt(10)" ::: "memory");
}
static __device__ __forceinline__ void wait_vm5() {
  asm volatile("s_waitcnt vmcnt(5)" ::: "memory");
}
static __device__ __forceinline__ void wait_vm3() {
  asm volatile("s_waitcnt vmcnt(3)" ::: "memory");
}
static __device__ __forceinline__ void wait_lgkm0() {
  asm volatile("s_waitcnt lgkmcnt(0)" ::: "memory");
  __builtin_amdgcn_sched_barrier(0);
}

// ---------------- CSR build ----------------
__global__ void k_count(const int* __restrict__ dst, int* __restrict__ counts, int e) {
  int i = blockIdx.x * blockDim.x + threadIdx.x;
  if (i < e) atomicAdd(&counts[dst[i]], 1);
}

__global__ __launch_bounds__(256) void k_scan_part(
    const int* __restrict__ counts, int* __restrict__ bsums, int n) {
  int tid = threadIdx.x;
  int i0 = blockIdx.x * 1024 + tid * 4;
  int s = 0;
#pragma unroll
  for (int k = 0; k < 4; k++) { int i = i0 + k; if (i < n) s += counts[i]; }
#pragma unroll
  for (int d = 1; d < 64; d <<= 1) s += __shfl_xor(s, d);
  __shared__ int wsum[4];
  int lane = tid & 63, w = tid >> 6;
  if (lane == 0) wsum[w] = s;
  __syncthreads();
  if (tid == 0) bsums[blockIdx.x] = wsum[0] + wsum[1] + wsum[2] + wsum[3];
}

// offsets + dinv + (counts -> 0, becoming fill cursor); folds scan_top.
__global__ __launch_bounds__(256) void k_scan_down(
    int* __restrict__ counts, const int* __restrict__ bsums,
    int* __restrict__ offsets, float* __restrict__ dinv, int n, int e, int nb) {
  int tid = threadIdx.x;
  int lane = tid & 63, w = tid >> 6;
  __shared__ int wsum[4], psum[4];
  int pv = (tid < nb && tid < blockIdx.x) ? bsums[tid] : 0;
#pragma unroll
  for (int d = 1; d < 64; d <<= 1) pv += __shfl_xor(pv, d);
  if (lane == 0) psum[w] = pv;
  __syncthreads();
  int blockpref = psum[0] + psum[1] + psum[2] + psum[3];

  int i0 = blockIdx.x * 1024 + tid * 4;
  int c[4]; int tsum = 0;
#pragma unroll
  for (int k = 0; k < 4; k++) { int i = i0 + k; c[k] = (i < n) ? counts[i] : 0; tsum += c[k]; }
  int v = tsum;
#pragma unroll
  for (int d = 1; d < 64; d <<= 1) { int t = __shfl_up(v, d); if (lane >= d) v += t; }
  if (lane == 63) wsum[w] = v;
  __syncthreads();
  int wadd = 0;
#pragma unroll
  for (int q = 0; q < 4; q++) if (q < w) wadd += wsum[q];
  int run = (v - tsum) + wadd + blockpref;
#pragma unroll
  for (int k = 0; k < 4; k++) {
    int i = i0 + k;
    if (i < n) {
      offsets[i] = run;
      dinv[i] = rsqrtf((float)(c[k] + 1));
      counts[i] = 0;
    }
    run += c[k];
  }
  if (blockIdx.x == 0 && tid == 0) offsets[n] = e;
}

__global__ void k_fill(const int* __restrict__ src, const int* __restrict__ dst,
                       const int* __restrict__ offsets, int* __restrict__ cursor,
                       const float* __restrict__ dinv, int2* __restrict__ csr, int e) {
  int i = blockIdx.x * blockDim.x + threadIdx.x;
  if (i >= e) return;
  int s = src[i], d = dst[i];
  int pos = atomicAdd(&cursor[d], 1);
  csr[offsets[d] + pos] = make_int2(s, __float_as_int(dinv[s] * dinv[d]));
}

// ---------------- weight prepack (fragment-ordered fp16, hi only) ----------
__device__ __forceinline__ void pack_hi(const float* __restrict__ W,
                                        _Float16* __restrict__ dst,
                                        int K, int N, int u) {
  int lane = u & 63; int rest = u >> 6; int CT = N >> 4;
  int ct = rest % CT, ks = rest / CT;
  int gcol = ct * 16 + (lane & 15);
  int gk0 = ks * 32 + (lane >> 4) * 8;
  size_t o = (size_t)(ks * CT + ct) * 512 + lane * 8;
#pragma unroll
  for (int i = 0; i < 8; i++) {
    float v = (gk0 + i < K) ? W[(size_t)(gk0 + i) * N + gcol] : 0.0f;
    dst[o + i] = (_Float16)v;
  }
}

__global__ void k_setup(const float* __restrict__ Wi, const float* __restrict__ Wg1,
                        const float* __restrict__ Wg2, const float* __restrict__ Wg3,
                        _Float16* __restrict__ pWi, _Float16* __restrict__ pWg1,
                        _Float16* __restrict__ pWg2, _Float16* __restrict__ pWg3,
                        int* __restrict__ counts, float* __restrict__ zp, int n) {
  int b = blockIdx.x;
  if (b < 25) {
    int t = b * 256 + threadIdx.x;
    if (t < 3072) pack_hi(Wi, pWi, 164, 128, t);
    else if (t < 5120) pack_hi(Wg1, pWg1, 128, 128, t - 3072);
    else if (t < 6144) pack_hi(Wg2, pWg2, 128, 64, t - 5120);
    else if (t < 6400) pack_hi(Wg3, pWg3, 64, 32, t - 6144);
  } else {
    if (b == 25 && threadIdx.x < 64) zp[threadIdx.x] = 0.0f;
    int i = (b - 25) * 256 + threadIdx.x;
    if (i < n) counts[i] = 0;
  }
}

// ---------------- input GEMM: h = LN(relu(x@Wi+bi)) ----------------
// Barrier-free wave-private A-DMA + register-double-buffered B prefetch.
// Per iter ks: issue B(ks+1)x8 + DMA(ks+1)x2, wait vmcnt(10) -> drains
// B(ks)+DMA(ks) (issued last iter); MFMA(ks) hides the new loads.
__global__ __launch_bounds__(512, 4) void k_gemm_in(
    const float* __restrict__ x, const _Float16* __restrict__ pB,
    const float* __restrict__ bias, const float* __restrict__ gamma,
    const float* __restrict__ beta, const float* __restrict__ zp,
    _Float16* __restrict__ out, int n) {
  constexpr int N = 128, CT = 8, KS = 6;
  __shared__ __align__(16) float sAi[8][2][512];  // 8 waves x 2 bufs x 2KB
  int tid = threadIdx.x;
  int lane = tid & 63, w = tid >> 6;
  int rowbase = blockIdx.x * 128 + w * 16;
  const f16x8* Bf = (const f16x8*)pB;

  auto stage = [&](int ks, int buf) {
#pragma unroll
    for (int j = 0; j < 2; j++) {
      int r_ = j * 8 + (lane >> 3);
      int c_ = (lane & 7) ^ (lane >> 3);
      int rg = rowbase + r_;
      bool ok = (rg < n) && (ks < 5 || c_ == 0);
      const void* s = ok ? (const void*)(x + (size_t)rg * 164 + ks * 32 + c_ * 4)
                         : (const void*)zp;
      GLOAD_LDS16(s, &sAi[w][buf][j * 256]);
    }
  };

  f32x4 acc[CT];
#pragma unroll
  for (int c = 0; c < CT; c++) acc[c] = (f32x4)0.0f;

  int rr = lane & 15;
  int c0 = (lane >> 4) * 2;
  int s0 = c0 ^ (rr & 7);
  int s1 = (c0 + 1) ^ (rr & 7);

  f16x8 bfr[2][CT];
#pragma unroll
  for (int c = 0; c < CT; c++) bfr[0][c] = Bf[c * 64 + lane];
  stage(0, 0);

#pragma unroll
  for (int ks = 0; ks < KS; ks++) {
    if (ks + 1 < KS) {
#pragma unroll
      for (int c = 0; c < CT; c++)
        bfr[(ks + 1) & 1][c] = Bf[((ks + 1) * CT + c) * 64 + lane];
      stage(ks + 1, (ks + 1) & 1);
      wait_vm10();
    } else {
      wait_vm0();
    }
    const float* bp = &sAi[w][ks & 1][0];
    float4 u0 = *(const float4*)&bp[rr * 32 + s0 * 4];
    float4 u1 = *(const float4*)&bp[rr * 32 + s1 * 4];
    float v[8] = {u0.x, u0.y, u0.z, u0.w, u1.x, u1.y, u1.z, u1.w};
    f16x8 ah;
#pragma unroll
    for (int i = 0; i < 8; i++) ah[i] = (_Float16)v[i];
#pragma unroll
    for (int c = 0; c < CT; c++)
      acc[c] = __builtin_amdgcn_mfma_f32_16x16x32_f16(ah, bfr[ks & 1][c], acc[c], 0, 0, 0);
  }

  // bias + relu + LN over N cols (row lives in a 16-lane group; wave-local)
  int r0 = (lane >> 4) * 4;
  int li = lane & 15;
  float s1v[4] = {0, 0, 0, 0}, s2v[4] = {0, 0, 0, 0};
#pragma unroll
  for (int c = 0; c < CT; c++) {
    float bb = bias[c * 16 + li];
#pragma unroll
    for (int r = 0; r < 4; r++) {
      float t = acc[c][r] + bb;
      t = t > 0.0f ? t : 0.0f;
      acc[c][r] = t;
      s1v[r] += t;
      s2v[r] += t * t;
    }
  }
#pragma unroll
  for (int m = 1; m < 16; m <<= 1) {
#pragma unroll
    for (int r = 0; r < 4; r++) {
      s1v[r] += __shfl_xor(s1v[r], m);
      s2v[r] += __shfl_xor(s2v[r], m);
    }
  }
  // repack through wave-private LDS -> coalesced f16x8 stores
  wait_lgkm0();
  _Float16* lr = (_Float16*)&sAi[w][0][0];  // 16 rows x 128 f16 = 4KB
#pragma unroll
  for (int c = 0; c < CT; c++) {
    float gv = gamma[c * 16 + li], bv = beta[c * 16 + li];
#pragma unroll
    for (int r = 0; r < 4; r++) {
      float mean = s1v[r] * (1.0f / N);
      float var = s2v[r] * (1.0f / N) - mean * mean;
      float rs = rsqrtf(var + 1e-5f);
      lr[(r0 + r) * 128 + c * 16 + li] =
          (_Float16)((acc[c][r] - mean) * rs * gv + bv);
    }
  }
  wait_lgkm0();
#pragma unroll
  for (int i = 0; i < 4; i++) {
    int chunk = i * 64 + lane;
    int rloc = chunk >> 4;
    int cc = chunk & 15;
    if (rowbase + rloc < n)
      *(f16x8*)&out[(size_t)(rowbase + rloc) * 128 + cc * 8] =
          *(const f16x8*)&lr[chunk * 8];
  }
}

// ---------------- conv GEMM: xw = A@W (fp16 x fp16-hi) ---------------------
// Same pipeline: B(ks+1)xCT + DMA(ks+1)x1 issued, wait vmcnt(CT+1).
template <int K, int N>
__global__ __launch_bounds__(512, 4) void k_gemm_f16(
    const _Float16* __restrict__ A, const _Float16* __restrict__ pB,
    const float* __restrict__ zp, _Float16* __restrict__ out, int n) {
  constexpr int KS = K / 32, CT = N / 16;
  __shared__ __align__(16) _Float16 sA[8][2][512];
  __shared__ __align__(16) _Float16 sR[8][16 * N];
  int tid = threadIdx.x;
  int lane = tid & 63, w = tid >> 6;
  int rowbase = blockIdx.x * 128 + w * 16;
  const f16x8* Bf = (const f16x8*)pB;

  int r_ = lane >> 2;
  int c_ = (lane & 3) ^ (r_ & 3);
  int rg = rowbase + r_;
  const _Float16* asrc = A + (size_t)rg * K + c_ * 8;
  bool rok = rg < n;

  auto stage = [&](int ks, int buf) {
    const void* s = rok ? (const void*)(asrc + ks * 32) : (const void*)zp;
    GLOAD_LDS16(s, &sA[w][buf][0]);
  };

  f32x4 acc[CT];
#pragma unroll
  for (int c = 0; c < CT; c++) acc[c] = (f32x4)0.0f;

  int rr = lane & 15;
  int slot = (lane >> 4) ^ (rr & 3);

  f16x8 bfr[2][CT];
#pragma unroll
  for (int c = 0; c < CT; c++) bfr[0][c] = Bf[c * 64 + lane];
  stage(0, 0);

#pragma unroll
  for (int ks = 0; ks < KS; ks++) {
    if (ks + 1 < KS) {
#pragma unroll
      for (int c = 0; c < CT; c++)
        bfr[(ks + 1) & 1][c] = Bf[((ks + 1) * CT + c) * 64 + lane];
      stage(ks + 1, (ks + 1) & 1);
      if (CT == 8) wait_vm10(); else if (CT == 4) wait_vm5(); else wait_vm3();
    } else {
      wait_vm0();
    }
    f16x8 av = *(const f16x8*)&sA[w][ks & 1][rr * 32 + slot * 8];
#pragma unroll
    for (int c = 0; c < CT; c++)
      acc[c] = __builtin_amdgcn_mfma_f32_16x16x32_f16(av, bfr[ks & 1][c], acc[c], 0, 0, 0);
  }

  int r0 = (lane >> 4) * 4;
  int li = lane & 15;
  wait_lgkm0();
  _Float16* lr = &sR[w][0];
#pragma unroll
  for (int c = 0; c < CT; c++) {
#pragma unroll
    for (int r = 0; r < 4; r++)
      lr[(r0 + r) * N + c * 16 + li] = (_Float16)acc[c][r];
  }
  wait_lgkm0();
#pragma unroll
  for (int i = 0; i < N / 32; i++) {
    int chunk = i * 64 + lane;
    int rloc = chunk / (N / 8);
    int cc = chunk % (N / 8);
    if (rowbase + rloc < n)
      *(f16x8*)&out[(size_t)(rowbase + rloc) * N + cc * 8] =
          *(const f16x8*)&lr[chunk * 8];
  }
}

// ---------------- dst-side gather, 4 cols/thread, 8-deep load batches ------
// MODE 0: out = relu(agg) + auxh[node]      (conv1)
// MODE 1: out = LN(relu(agg); gamma, beta)  (conv2)
// MODE 2: out = agg                         (conv3; tail applies relu)
template <int OUT_D, int MODE>
__global__ __launch_bounds__(256, 2) void k_gather(
    const int* __restrict__ off, const int2* __restrict__ csr,
    const _Float16* __restrict__ xw, const float* __restrict__ dinv,
    const float* __restrict__ bias, const _Float16* __restrict__ auxh,
    const float* __restrict__ gamma, const float* __restrict__ beta,
    _Float16* __restrict__ out, int n) {
  constexpr int TPN = OUT_D / 4;
  constexpr int NPB = 256 / TPN;
  int tid = threadIdx.x;
  int node = blockIdx.x * NPB + tid / TPN;
  int li = tid % TPN;
  if (node >= n) return;
  int start = off[node], end = off[node + 1];
  float di = dinv[node];
  float d2 = di * di;
  const _Float16* xp = xw + 4 * li;
  f16x4 self = *(const f16x4*)(xp + (size_t)node * OUT_D);
  f16x4 hres;
  if constexpr (MODE == 0)
    hres = *(const f16x4*)(auxh + (size_t)node * OUT_D + 4 * li);
  float a0 = (float)self[0] * d2 + bias[4 * li + 0];
  float a1 = (float)self[1] * d2 + bias[4 * li + 1];
  float a2 = (float)self[2] * d2 + bias[4 * li + 2];
  float a3 = (float)self[3] * d2 + bias[4 * li + 3];
  for (int cb = start; cb < end; cb += TPN) {
    int m = end - cb; if (m > TPN) m = TPN;
    int sv = node; float nv = 0.0f;
    if (li < m) { int2 me = csr[cb + li]; sv = me.x; nv = __int_as_float(me.y); }
    for (int j0 = 0; j0 < m; j0 += 8) {
      int s0 = __shfl(sv, j0 + 0, TPN), s1 = __shfl(sv, j0 + 1, TPN);
      int s2 = __shfl(sv, j0 + 2, TPN), s3 = __shfl(sv, j0 + 3, TPN);
      int s4 = __shfl(sv, j0 + 4, TPN), s5 = __shfl(sv, j0 + 5, TPN);
      int s6 = __shfl(sv, j0 + 6, TPN), s7 = __shfl(sv, j0 + 7, TPN);
      float w0 = __shfl(nv, j0 + 0, TPN), w1 = __shfl(nv, j0 + 1, TPN);
      float w2 = __shfl(nv, j0 + 2, TPN), w3 = __shfl(nv, j0 + 3, TPN);
      float w4 = __shfl(nv, j0 + 4, TPN), w5 = __shfl(nv, j0 + 5, TPN);
      float w6 = __shfl(nv, j0 + 6, TPN), w7 = __shfl(nv, j0 + 7, TPN);
      f16x4 v0 = *(const f16x4*)(xp + (size_t)s0 * OUT_D);
      f16x4 v1 = *(const f16x4*)(xp + (size_t)s1 * OUT_D);
      f16x4 v2 = *(const f16x4*)(xp + (size_t)s2 * OUT_D);
      f16x4 v3 = *(const f16x4*)(xp + (size_t)s3 * OUT_D);
      f16x4 v4 = *(const f16x4*)(xp + (size_t)s4 * OUT_D);
      f16x4 v5 = *(const f16x4*)(xp + (size_t)s5 * OUT_D);
      f16x4 v6 = *(const f16x4*)(xp + (size_t)s6 * OUT_D);
      f16x4 v7 = *(const f16x4*)(xp + (size_t)s7 * OUT_D);
      a0 += (float)v0[0] * w0 + (float)v1[0] * w1 + (float)v2[0] * w2 + (float)v3[0] * w3
          + (float)v4[0] * w4 + (float)v5[0] * w5 + (float)v6[0] * w6 + (float)v7[0] * w7;
      a1 += (float)v0[1] * w0 + (float)v1[1] * w1 + (float)v2[1] * w2 + (float)v3[1] * w3
          + (float)v4[1] * w4 + (float)v5[1] * w5 + (float)v6[1] * w6 + (float)v7[1] * w7;
      a2 += (float)v0[2] * w0 + (float)v1[2] * w1 + (float)v2[2] * w2 + (float)v3[2] * w3
          + (float)v4[2] * w4 + (float)v5[2] * w5 + (float)v6[2] * w6 + (float)v7[2] * w7;
      a3 += (float)v0[3] * w0 + (float)v1[3] * w1 + (float)v2[3] * w2 + (float)v3[3] * w3
          + (float)v4[3] * w4 + (float)v5[3] * w5 + (float)v6[3] * w6 + (float)v7[3] * w7;
    }
  }
  _Float16* po = out + (size_t)node * OUT_D + 4 * li;
  if constexpr (MODE == 0) {
    f16x4 o;
    o[0] = (_Float16)((a0 > 0.0f ? a0 : 0.0f) + (float)hres[0]);
    o[1] = (_Float16)((a1 > 0.0f ? a1 : 0.0f) + (float)hres[1]);
    o[2] = (_Float16)((a2 > 0.0f ? a2 : 0.0f) + (float)hres[2]);
    o[3] = (_Float16)((a3 > 0.0f ? a3 : 0.0f) + (float)hres[3]);
    *(f16x4*)po = o;
  } else if constexpr (MODE == 1) {
    float v0 = a0 > 0.0f ? a0 : 0.0f, v1 = a1 > 0.0f ? a1 : 0.0f;
    float v2 = a2 > 0.0f ? a2 : 0.0f, v3 = a3 > 0.0f ? a3 : 0.0f;
    float s1 = v0 + v1 + v2 + v3;
    float s2 = v0 * v0 + v1 * v1 + v2 * v2 + v3 * v3;
#pragma unroll
    for (int d = 1; d < TPN; d <<= 1) {
      s1 += __shfl_xor(s1, d, TPN);
      s2 += __shfl_xor(s2, d, TPN);
    }
    float m_ = s1 * (1.0f / OUT_D);
    float var = s2 * (1.0f / OUT_D) - m_ * m_;
    float rs = rsqrtf(var + 1e-5f);
    f16x4 o;
    o[0] = (_Float16)((v0 - m_) * rs * gamma[4 * li + 0] + beta[4 * li + 0]);
    o[1] = (_Float16)((v1 - m_) * rs * gamma[4 * li + 1] + beta[4 * li + 1]);
    o[2] = (_Float16)((v2 - m_) * rs * gamma[4 * li + 2] + beta[4 * li + 2]);
    o[3] = (_Float16)((v3 - m_) * rs * gamma[4 * li + 3] + beta[4 * li + 3]);
    *(f16x4*)po = o;
  } else {
    f16x4 o;
    o[0] = (_Float16)a0; o[1] = (_Float16)a1;
    o[2] = (_Float16)a2; o[3] = (_Float16)a3;
    *(f16x4*)po = o;
  }
}

// ---------------- tail: relu(agg3) -> Wv -> Wo -> Wc1 -> Wc2 -> Wc3 --------
__global__ __launch_bounds__(256) void k_tail(
    const _Float16* __restrict__ agg3, const float* __restrict__ Wv,
    const float* __restrict__ bv, const float* __restrict__ Wo,
    const float* __restrict__ bo, const float* __restrict__ Wc1,
    const float* __restrict__ bc1, const float* __restrict__ Wc2,
    const float* __restrict__ bc2, const float* __restrict__ Wc3,
    const float* __restrict__ bc3, float* __restrict__ out, int n) {
  __shared__ float sWv[1024], sWo[1024], sWc1[512], sWc2[512];
  __shared__ float sbv[32], sbo[32], sbc2[32], sWc3[32], sbc1[16], sbc3[1];
  int tid = threadIdx.x;
  for (int i = tid; i < 1024; i += 256) { sWv[i] = Wv[i]; sWo[i] = Wo[i]; }
  for (int i = tid; i < 512; i += 256) { sWc1[i] = Wc1[i]; sWc2[i] = Wc2[i]; }
  if (tid < 32) { sbv[tid] = bv[tid]; sbo[tid] = bo[tid];
                  sbc2[tid] = bc2[tid]; sWc3[tid] = Wc3[tid]; }
  if (tid < 16) sbc1[tid] = bc1[tid];
  if (tid == 0) sbc3[0] = bc3[0];
  __syncthreads();
  int node = blockIdx.x * blockDim.x + tid;
  if (node >= n) return;
  float a[32];
  const f16x8* row8 = (const f16x8*)(agg3 + (size_t)node * 32);
#pragma unroll
  for (int q = 0; q < 4; q++) {
    f16x8 t = row8[q];
#pragma unroll
    for (int i = 0; i < 8; i++) {
      float f = (float)t[i];
      a[8 * q + i] = f > 0.0f ? f : 0.0f;
    }
  }
  float v[32];
#pragma unroll
  for (int j = 0; j < 32; j++) v[j] = sbv[j];
  for (int k = 0; k < 32; k++) {
#pragma unroll
    for (int j = 0; j < 32; j++) v[j] += a[k] * sWv[k * 32 + j];
  }
  float o[32];
#pragma unroll
  for (int j = 0; j < 32; j++) o[j] = sbo[j];
  for (int k = 0; k < 32; k++) {
#pragma unroll
    for (int j = 0; j < 32; j++) o[j] += v[k] * sWo[k * 32 + j];
  }
  float c1[16];
#pragma unroll
  for (int j = 0; j < 16; j++) c1[j] = sbc1[j];
  for (int k = 0; k < 32; k++) {
#pragma unroll
    for (int j = 0; j < 16; j++) c1[j] += o[k] * sWc1[k * 16 + j];
  }
#pragma unroll
  for (int j = 0; j < 16; j++) c1[j] = c1[j] > 0.0f ? c1[j] : 0.0f;
  float c2[32];
#pragma unroll
  for (int j = 0; j < 32; j++) c2[j] = sbc2[j];
  for (int k = 0; k < 16; k++) {
#pragma unroll
    for (int j = 0; j < 32; j++) c2[j] += c1[k] * sWc2[k * 32 + j];
  }
  float r = sbc3[0];
#pragma unroll
  for (int k = 0; k < 32; k++) {
    float c = c2[k] > 0.0f ? c2[k] : 0.0f;
    r += c * sWc3[k];
  }
  out[node] = r;
}

// ---------------------------------------------------------------------------
extern "C" void kernel_launch(void* const* d_in, const int* in_sizes, int n_in,
                              void* d_out, int out_size, void* d_ws, size_t ws_size,
                              hipStream_t stream) {
  const float* x   = (const float*)d_in[0];
  const int* ei    = (const int*)d_in[1];
  const float* Wi  = (const float*)d_in[2];
  const float* bi  = (const float*)d_in[3];
  const float* g1  = (const float*)d_in[4];
  const float* b1  = (const float*)d_in[5];
  const float* Wg1 = (const float*)d_in[6];
  const float* bg1 = (const float*)d_in[7];
  const float* Wg2 = (const float*)d_in[8];
  const float* bg2 = (const float*)d_in[9];
  const float* g2  = (const float*)d_in[10];
  const float* b2  = (const float*)d_in[11];
  const float* Wg3 = (const float*)d_in[12];
  const float* bg3 = (const float*)d_in[13];
  // d_in[14..17]: Wq,bq,Wk,bk — mathematically dead (softmax over 1 key == 1)
  const float* Wv  = (const float*)d_in[18];
  const float* bv  = (const float*)d_in[19];
  const float* Wo  = (const float*)d_in[20];
  const float* bo  = (const float*)d_in[21];
  const float* Wc1 = (const float*)d_in[22];
  const float* bc1 = (const float*)d_in[23];
  const float* Wc2 = (const float*)d_in[24];
  const float* bc2 = (const float*)d_in[25];
  const float* Wc3 = (const float*)d_in[26];
  const float* bc3 = (const float*)d_in[27];

  const int n = in_sizes[0] / 164;
  const int e = in_sizes[1] / 2;
  const int* src = ei;
  const int* dst = ei + e;

  // workspace layout (256B aligned)
  char* ws = (char*)d_ws;
  size_t off = 0;
  auto alloc = [&](size_t bytes) {
    char* p = ws + off;
    off += (bytes + 255) & ~(size_t)255;
    return p;
  };
  _Float16* A     = (_Float16*)alloc((size_t)n * 128 * 2);
  _Float16* B     = (_Float16*)alloc((size_t)n * 128 * 2);
  _Float16* C     = (_Float16*)alloc((size_t)n * 128 * 2);
  float* dinv     = (float*)alloc((size_t)n * 4);
  int*   counts   = (int*)alloc((size_t)n * 4);
  int*   offsets  = (int*)alloc((size_t)(n + 1) * 4);
  int*   bsums    = (int*)alloc(256 * 4);
  int2*  csr      = (int2*)alloc((size_t)e * 8);
  _Float16* pWi   = (_Float16*)alloc(3072 * 16);
  _Float16* pWg1  = (_Float16*)alloc(2048 * 16);
  _Float16* pWg2  = (_Float16*)alloc(1024 * 16);
  _Float16* pWg3  = (_Float16*)alloc(256 * 16);
  float* zp       = (float*)alloc(64 * 4);
  (void)ws_size;

  const int BS = 256;
  const int SB = (n + 1023) / 1024;
  const int GB = (n + 127) / 128;

  // ---- setup ----
  k_setup<<<25 + (n + 255) / 256, 256, 0, stream>>>(
      Wi, Wg1, Wg2, Wg3, pWi, pWg1, pWg2, pWg3, counts, zp, n);

  // ---- CSR build ----
  k_count<<<(e + BS - 1) / BS, BS, 0, stream>>>(dst, counts, e);
  k_scan_part<<<SB, 256, 0, stream>>>(counts, bsums, n);
  k_scan_down<<<SB, 256, 0, stream>>>(counts, bsums, offsets, dinv, n, e, SB);
  k_fill<<<(e + BS - 1) / BS, BS, 0, stream>>>(src, dst, offsets, counts, dinv,
                                               csr, e);

  // ---- input layer ----
  k_gemm_in<<<GB, 512, 0, stream>>>(x, pWi, bi, g1, b1, zp, A, n);

  // ---- conv1 ----
  k_gemm_f16<128, 128><<<GB, 512, 0, stream>>>(A, pWg1, zp, B, n);
  k_gather<128, 0><<<(n + 7) / 8, 256, 0, stream>>>(
      offsets, csr, B, dinv, bg1, A, nullptr, nullptr, C, n);

  // ---- conv2 ----
  k_gemm_f16<128, 64><<<GB, 512, 0, stream>>>(C, pWg2, zp, A, n);
  k_gather<64, 1><<<(n + 15) / 16, 256, 0, stream>>>(
      offsets, csr, A, dinv, bg2, nullptr, g2, b2, B, n);

  // ---- conv3 ----
  k_gemm_f16<64, 32><<<GB, 512, 0, stream>>>(B, pWg3, zp, A, n);
  k_gather<32, 2><<<(n + 31) / 32, 256, 0, stream>>>(
      offsets, csr, A, dinv, bg3, nullptr, nullptr, nullptr, C, n);

  // ---- tail ----
  k_tail<<<(n + BS - 1) / BS, BS, 0, stream>>>(
      C, Wv, bv, Wo, bo, Wc1, bc1, Wc2, bc2, Wc3, bc3, (float*)d_out, n);
}